// Round 2
// baseline (339.042 us; speedup 1.0000x reference)
//
#include <hip/hip_runtime.h>

// ---------------- problem constants (match reference) ----------------
#define ES 256
#define B_DIM 8192
#define N_DIM 12
#define NFEAT 42
#define NENT (B_DIM * N_DIM)   // 98304 entities

// feature indices
#define F_SPECIES 0
#define F_ABILITY 1
#define F_ITEM 2
#define F_ITEM_EFFECT 3
#define F_GENDER 4
#define F_STATUS 5
#define F_BCB 6
#define F_TRAPPED 7
#define F_NEWSW 8
#define F_TOXIC 9
#define F_SLEEP 10
#define F_FAINTED 11
#define F_ACTIVE 12
#define F_SIDE 13
#define F_LEVEL 14
#define F_HP 15
#define F_MAXHP 16
#define F_BOOST0 17   // 7 boosts: 17..23
#define F_VOL0 24     // 9 vols: 24..32 (only first 7 matter after [:105] truncation)
#define F_MOVEID0 33  // 4 move ids
#define F_MOVEPP0 37  // 4 move pp

// ---------------- workspace layout (floats) ----------------
// Hp:    1024 rows  (10-bit hp-token bit-sum of hp_W)
// Lv:     128 rows  (7-bit level bit-sum of level_W)
// Pp:      64 rows  (6-bit movepp bit-sum of moves_W[256:262])
// VP:     784 rows  (vol nibble-pair tables: 3x256 pair + 16 single)
// combA:  768 rows  (item_effect x gender x bcb x trapped x newsw x fainted)
// combB: 1024 rows  (status x toxic x sleep x active x side  + all biases)
// Eitem:  500 rows  (embed_item @ item_W[:256])
// Emoves: 920 rows  (embed_moves @ moves_W[:256])
#define OFF_HP     0
#define OFF_LV     (OFF_HP + 1024*ES)
#define OFF_PP     (OFF_LV + 128*ES)
#define OFF_VP     (OFF_PP + 64*ES)
#define OFF_CA     (OFF_VP + 784*ES)
#define OFF_CB     (OFF_CA + 768*ES)
#define OFF_EITEM  (OFF_CB + 1024*ES)
#define OFF_EMOVES (OFF_EITEM + 500*ES)
#define WS_FLOATS  (OFF_EMOVES + 920*ES)   // ~5.2 MB

// ---------------- precompute kernels ----------------

// out[v][d] = sum_{b<nbits, bit b of v set} W[b][d];  grid = (1<<nbits) x 256
__global__ void k_bits_table(const float* __restrict__ W, int nbits, float* __restrict__ out) {
    int v = blockIdx.x, d = threadIdx.x;
    float acc = 0.f;
    for (int b = 0; b < nbits; ++b)
        if ((v >> b) & 1) acc += W[b * ES + d];
    out[v * ES + d] = acc;
}

// Volatile nibble-pair tables.  grid = 784 x 256.
// bid < 768: t = bid>>8 (segment pair 2t,2t+1), pair = bid&255 = (a<<4)|b
//   row = sum_{j<16}[ (a&j)!=0 ] volW[(32t+j)] + [ (b&j)!=0 ] volW[(32t+16+j)]
// bid >= 768: single nibble table for segment 6 (rows 96..104 only, [:105] trunc)
__global__ void k_volpair(const float* __restrict__ W, float* __restrict__ out) {
    int bid = blockIdx.x, d = threadIdx.x;
    float acc = 0.f;
    if (bid < 768) {
        int t = bid >> 8, pair = bid & 255, a = pair >> 4, b = pair & 15;
        for (int j = 0; j < 16; ++j) {
            if (a & j) acc += W[(32 * t + j) * ES + d];
            if (b & j) acc += W[(32 * t + 16 + j) * ES + d];
        }
    } else {
        int a = bid - 768;
        for (int j = 0; j < 9; ++j)          // rows 96..104 < 105
            if (a & j) acc += W[(96 + j) * ES + d];
    }
    out[bid * ES + d] = acc;
}

// combA: idx = ((((e*3+g)*2+bcb)*2+tr)*2+ns)*2+fa   (768 rows)
__global__ void k_combA(const float* __restrict__ itemW, const float* __restrict__ onehotW,
                        float* __restrict__ out) {
    int idx = blockIdx.x, d = threadIdx.x;
    int fa = idx & 1, ns = (idx >> 1) & 1, tr = (idx >> 2) & 1, bcb = (idx >> 3) & 1;
    int rest = idx >> 4, g = rest % 3, e = rest / 3;
    out[idx * ES + d] = itemW[(256 + e) * ES + d] + onehotW[(1 + g) * ES + d] +
                        onehotW[(12 + bcb) * ES + d] + onehotW[(14 + tr) * ES + d] +
                        onehotW[(16 + ns) * ES + d] + onehotW[(30 + fa) * ES + d];
}

// combB: idx = (((st*8+tox)*4+sl)*2+act)*2+sd   (1024 rows), bias folded in
__global__ void k_combB(const float* __restrict__ onehotW, const float* __restrict__ activeW,
                        const float* __restrict__ sideW,
                        const float* __restrict__ hp_b, const float* __restrict__ level_b,
                        const float* __restrict__ active_b, const float* __restrict__ onehot_b,
                        const float* __restrict__ boosts_b, const float* __restrict__ vol_b,
                        const float* __restrict__ item_b, const float* __restrict__ side_b,
                        const float* __restrict__ moves_b,
                        float* __restrict__ out) {
    int idx = blockIdx.x, d = threadIdx.x;
    int sd = idx & 1, act = (idx >> 1) & 1, sl = (idx >> 2) & 3, tox = (idx >> 4) & 7, st = idx >> 7;
    float bias = hp_b[d] + level_b[d] + active_b[d] + onehot_b[d] + boosts_b[d] +
                 vol_b[d] + item_b[d] + side_b[d] + 4.0f * moves_b[d];
    out[idx * ES + d] = bias + onehotW[(4 + st) * ES + d] + onehotW[(18 + tox) * ES + d] +
                        onehotW[(26 + sl) * ES + d] + activeW[act * ES + d] + sideW[sd * ES + d];
}

// out[r][d] = sum_k E[r][k] * W[k][d] over k<256.  4 rows/block, 256 threads.
__global__ void k_embmm(const float* __restrict__ E, const float* __restrict__ W,
                        int nrows, float* __restrict__ out) {
    __shared__ float se[4][ES];
    int tid = threadIdx.x;
    int r0 = blockIdx.x * 4;
    for (int i = tid; i < 4 * ES; i += 256) {
        int r = r0 + (i >> 8);
        se[i >> 8][i & 255] = (r < nrows) ? E[r * ES + (i & 255)] : 0.f;
    }
    __syncthreads();
    int rl = tid >> 6, lane = tid & 63, d0 = lane * 4;
    int r = r0 + rl;
    if (r >= nrows) return;
    float4 acc = make_float4(0.f, 0.f, 0.f, 0.f);
#pragma unroll 4
    for (int k = 0; k < ES; ++k) {
        float e = se[rl][k];
        const float4 w = *reinterpret_cast<const float4*>(&W[k * ES + d0]);
        acc.x += e * w.x; acc.y += e * w.y; acc.z += e * w.z; acc.w += e * w.w;
    }
    *reinterpret_cast<float4*>(&out[r * ES + d0]) = acc;
}

// ---------------- main gather/accumulate kernel ----------------

__device__ __forceinline__ float4 ld4(const float* p) {
    return *reinterpret_cast<const float4*>(p);
}
__device__ __forceinline__ void add4(float4& a, const float4 b) {
    a.x += b.x; a.y += b.y; a.z += b.z; a.w += b.w;
}
__device__ __forceinline__ void fma4(float4& a, float s, const float4 b) {
    a.x += s * b.x; a.y += s * b.y; a.z += s * b.z; a.w += s * b.w;
}
__device__ __forceinline__ int clampi(int x, int lo, int hi) {
    return x < lo ? lo : (x > hi ? hi : x);
}

__global__ __launch_bounds__(256) void k_main(
    const int* __restrict__ ent,
    const float* __restrict__ spW, const float* __restrict__ abW,
    const float* __restrict__ onehotW, const float* __restrict__ boostsW,
    const float* __restrict__ ws,
    float* __restrict__ out) {
    int wid = (blockIdx.x * 256 + threadIdx.x) >> 6;  // one wave per entity
    if (wid >= NENT) return;
    int lane = threadIdx.x & 63;
    int d0 = lane * 4;

    const float* Hp     = ws + OFF_HP;
    const float* Lv     = ws + OFF_LV;
    const float* Pp     = ws + OFF_PP;
    const float* VP     = ws + OFF_VP;
    const float* CA     = ws + OFF_CA;
    const float* CB     = ws + OFF_CB;
    const float* Eitem  = ws + OFF_EITEM;
    const float* Emoves = ws + OFF_EMOVES;

    const int* f = ent + wid * NFEAT;

    // combB (status,toxic,sleep,active,side) + all biases — always valid
    int idxB = ((((f[F_STATUS] & 7) * 8 + (f[F_TOXIC] & 7)) * 4 + (f[F_SLEEP] & 3)) * 2 +
                (f[F_ACTIVE] & 1)) * 2 + (f[F_SIDE] & 1);
    float4 acc = ld4(CB + idxB * ES + d0);

    // combA (item_effect,gender,bcb,trapped,newly_switched,fainted)
    int g = f[F_GENDER]; g = g > 2 ? 2 : g;
    int idxA = (((((f[F_ITEM_EFFECT] & 15) * 3 + g) * 2 + (f[F_BCB] & 1)) * 2 +
                 (f[F_TRAPPED] & 1)) * 2 + (f[F_NEWSW] & 1)) * 2 + (f[F_FAINTED] & 1);
    add4(acc, ld4(CA + idxA * ES + d0));

    // hp token + hp_ratio * onehot_W[0]
    float hp = (float)f[F_HP];
    int mh = f[F_MAXHP]; if (mh < 1) mh = 1;
    float ratio = fminf(fmaxf(hp / (float)mh, 0.f), 1.f);
    int tok = (int)floorf(1023.f * ratio);
    add4(acc, ld4(Hp + tok * ES + d0));
    fma4(acc, ratio, ld4(onehotW + d0));

    // level bits
    add4(acc, ld4(Lv + (f[F_LEVEL] & 127) * ES + d0));

    // boosts (scaled rows); wave-uniform skip when zero
#pragma unroll
    for (int k = 0; k < 7; ++k) {
        int bv = f[F_BOOST0 + k];
        if (bv != 0) fma4(acc, 0.5f * (float)bv, ld4(boostsW + k * ES + d0));
    }

    // volatiles via pair tables (k=0..5 pairs) + single (k=6)
#pragma unroll
    for (int t = 0; t < 3; ++t) {
        int pair = ((f[F_VOL0 + 2 * t] & 15) << 4) | (f[F_VOL0 + 2 * t + 1] & 15);
        if (pair != 0) add4(acc, ld4(VP + (t * 256 + pair) * ES + d0));
    }
    {
        int nib = f[F_VOL0 + 6] & 15;
        if (nib != 0) add4(acc, ld4(VP + (768 + nib) * ES + d0));
    }

    // species + ability embeddings
    add4(acc, ld4(spW + clampi(f[F_SPECIES], 0, 1025) * ES + d0));
    add4(acc, ld4(abW + clampi(f[F_ABILITY], 0, 299) * ES + d0));

    // item: precomputed embed_item @ item_W[:256]
    add4(acc, ld4(Eitem + clampi(f[F_ITEM], 0, 499) * ES + d0));

    // moves: 4 x (E_moves[id] + Pp[pp&63])
#pragma unroll
    for (int m = 0; m < 4; ++m) {
        int mid = clampi(f[F_MOVEID0 + m], 0, 919);
        add4(acc, ld4(Emoves + mid * ES + d0));
        int pp = f[F_MOVEPP0 + m] & 63;
        if (pp != 0) add4(acc, ld4(Pp + pp * ES + d0));
    }

    *reinterpret_cast<float4*>(&out[wid * ES + d0]) = acc;
}

// ---------------- host launch ----------------

extern "C" void kernel_launch(void* const* d_in, const int* in_sizes, int n_in,
                              void* d_out, int out_size, void* d_ws, size_t ws_size,
                              hipStream_t stream) {
    const int*   entities = (const int*)  d_in[0];
    const float* sp       = (const float*)d_in[1];
    const float* ab       = (const float*)d_in[2];
    const float* item_e   = (const float*)d_in[3];
    const float* moves_e  = (const float*)d_in[4];
    const float* hp_W     = (const float*)d_in[5];
    const float* hp_b     = (const float*)d_in[6];
    const float* level_W  = (const float*)d_in[7];
    const float* level_b  = (const float*)d_in[8];
    const float* active_W = (const float*)d_in[9];
    const float* active_b = (const float*)d_in[10];
    const float* onehot_W = (const float*)d_in[11];
    const float* onehot_b = (const float*)d_in[12];
    const float* boosts_W = (const float*)d_in[13];
    const float* boosts_b = (const float*)d_in[14];
    const float* vol_W    = (const float*)d_in[15];
    const float* vol_b    = (const float*)d_in[16];
    const float* item_W   = (const float*)d_in[17];
    const float* item_b   = (const float*)d_in[18];
    const float* side_W   = (const float*)d_in[19];
    const float* side_b   = (const float*)d_in[20];
    const float* moves_W  = (const float*)d_in[21];
    const float* moves_b  = (const float*)d_in[22];

    float* ws  = (float*)d_ws;
    float* out = (float*)d_out;

    // ---- per-launch precompute (weight-derived tables) ----
    k_bits_table<<<1024, 256, 0, stream>>>(hp_W, 10, ws + OFF_HP);
    k_bits_table<<<128, 256, 0, stream>>>(level_W, 7, ws + OFF_LV);
    k_bits_table<<<64, 256, 0, stream>>>(moves_W + 256 * ES, 6, ws + OFF_PP);
    k_volpair<<<784, 256, 0, stream>>>(vol_W, ws + OFF_VP);
    k_combA<<<768, 256, 0, stream>>>(item_W, onehot_W, ws + OFF_CA);
    k_combB<<<1024, 256, 0, stream>>>(onehot_W, active_W, side_W,
                                      hp_b, level_b, active_b, onehot_b, boosts_b,
                                      vol_b, item_b, side_b, moves_b, ws + OFF_CB);
    k_embmm<<<125, 256, 0, stream>>>(item_e, item_W, 500, ws + OFF_EITEM);
    k_embmm<<<230, 256, 0, stream>>>(moves_e, moves_W, 920, ws + OFF_EMOVES);

    // ---- main gather kernel: one wave per entity, 4 entities per block ----
    k_main<<<NENT / 4, 256, 0, stream>>>(entities, sp, ab, onehot_W, boosts_W, ws, out);
}

// Round 3
// 260.478 us; speedup vs baseline: 1.3016x; 1.3016x over previous
//
#include <hip/hip_runtime.h>

// ---------------- problem constants (match reference) ----------------
#define ES 256
#define B_DIM 8192
#define N_DIM 12
#define NFEAT 42
#define NENT (B_DIM * N_DIM)   // 98304 entities

// feature indices
#define F_SPECIES 0
#define F_ABILITY 1
#define F_ITEM 2
#define F_ITEM_EFFECT 3
#define F_GENDER 4
#define F_STATUS 5
#define F_BCB 6
#define F_TRAPPED 7
#define F_NEWSW 8
#define F_TOXIC 9
#define F_SLEEP 10
#define F_FAINTED 11
#define F_ACTIVE 12
#define F_SIDE 13
#define F_LEVEL 14
#define F_HP 15
#define F_MAXHP 16
#define F_BOOST0 17   // 7 boosts: 17..23
#define F_VOL0 24     // 9 vols: 24..32 (only first 7 matter after [:105] truncation)
#define F_MOVEID0 33  // 4 move ids
#define F_MOVEPP0 37  // 4 move pp

// ---------------- workspace layout (floats) ----------------
#define OFF_HP     0
#define OFF_LV     (OFF_HP + 1024*ES)
#define OFF_PP     (OFF_LV + 128*ES)
#define OFF_VP     (OFF_PP + 64*ES)
#define OFF_CA     (OFF_VP + 784*ES)
#define OFF_CB     (OFF_CA + 768*ES)
#define OFF_EITEM  (OFF_CB + 1024*ES)
#define OFF_EMOVES (OFF_EITEM + 500*ES)
#define WS_FLOATS  (OFF_EMOVES + 920*ES)   // ~5.3 MB

// ---------------- fused precompute kernel: blockIdx ranges ----------------
#define TB_HP0 0        // 1024 blocks: Hp (10-bit bit-sum of hp_W)
#define TB_LV0 1024     //  128 blocks: Lv (7-bit bit-sum of level_W)
#define TB_PP0 1152     //   64 blocks: Pp (6-bit bit-sum of moves_W[256:262])
#define TB_VP0 1216     //  784 blocks: volatile nibble-pair tables
#define TB_CA0 2000     //  768 blocks: combA
#define TB_CB0 2768     // 1024 blocks: combB (+ all biases)
#define TB_EI0 3792     //  125 blocks: Eitem = embed_item @ item_W[:256]
#define TB_EM0 3917     //  230 blocks: Emoves = embed_moves @ moves_W[:256]
#define TB_TOT 4147

__global__ __launch_bounds__(256) void k_tables(
    const float* __restrict__ item_e, const float* __restrict__ moves_e,
    const float* __restrict__ hp_W, const float* __restrict__ level_W,
    const float* __restrict__ moves_W, const float* __restrict__ vol_W,
    const float* __restrict__ item_W, const float* __restrict__ onehot_W,
    const float* __restrict__ active_W, const float* __restrict__ side_W,
    const float* __restrict__ hp_b, const float* __restrict__ level_b,
    const float* __restrict__ active_b, const float* __restrict__ onehot_b,
    const float* __restrict__ boosts_b, const float* __restrict__ vol_b,
    const float* __restrict__ item_b, const float* __restrict__ side_b,
    const float* __restrict__ moves_b,
    float* __restrict__ ws) {
    __shared__ float se[4][ES];
    int bid = blockIdx.x;
    int d = threadIdx.x;

    if (bid < TB_LV0) {                       // ---- Hp: 10-bit table
        int v = bid;
        float acc = 0.f;
        for (int b = 0; b < 10; ++b)
            if ((v >> b) & 1) acc += hp_W[b * ES + d];
        ws[OFF_HP + v * ES + d] = acc;
    } else if (bid < TB_PP0) {                // ---- Lv: 7-bit table
        int v = bid - TB_LV0;
        float acc = 0.f;
        for (int b = 0; b < 7; ++b)
            if ((v >> b) & 1) acc += level_W[b * ES + d];
        ws[OFF_LV + v * ES + d] = acc;
    } else if (bid < TB_VP0) {                // ---- Pp: 6-bit table
        int v = bid - TB_PP0;
        float acc = 0.f;
        for (int b = 0; b < 6; ++b)
            if ((v >> b) & 1) acc += moves_W[(256 + b) * ES + d];
        ws[OFF_PP + v * ES + d] = acc;
    } else if (bid < TB_CA0) {                // ---- VP: vol nibble pairs + single
        int v = bid - TB_VP0;
        float acc = 0.f;
        if (v < 768) {
            int t = v >> 8, pair = v & 255, a = pair >> 4, b = pair & 15;
            for (int j = 0; j < 16; ++j) {
                if (a & j) acc += vol_W[(32 * t + j) * ES + d];
                if (b & j) acc += vol_W[(32 * t + 16 + j) * ES + d];
            }
        } else {
            int a = v - 768;
            for (int j = 0; j < 9; ++j)       // rows 96..104 (< 105 truncation)
                if (a & j) acc += vol_W[(96 + j) * ES + d];
        }
        ws[OFF_VP + v * ES + d] = acc;
    } else if (bid < TB_CB0) {                // ---- combA
        int idx = bid - TB_CA0;
        int fa = idx & 1, ns = (idx >> 1) & 1, tr = (idx >> 2) & 1, bcb = (idx >> 3) & 1;
        int rest = idx >> 4, g = rest % 3, e = rest / 3;
        ws[OFF_CA + idx * ES + d] =
            item_W[(256 + e) * ES + d] + onehot_W[(1 + g) * ES + d] +
            onehot_W[(12 + bcb) * ES + d] + onehot_W[(14 + tr) * ES + d] +
            onehot_W[(16 + ns) * ES + d] + onehot_W[(30 + fa) * ES + d];
    } else if (bid < TB_EI0) {                // ---- combB (+ all biases)
        int idx = bid - TB_CB0;
        int sd = idx & 1, act = (idx >> 1) & 1, sl = (idx >> 2) & 3,
            tox = (idx >> 4) & 7, st = idx >> 7;
        float bias = hp_b[d] + level_b[d] + active_b[d] + onehot_b[d] + boosts_b[d] +
                     vol_b[d] + item_b[d] + side_b[d] + 4.0f * moves_b[d];
        ws[OFF_CB + idx * ES + d] =
            bias + onehot_W[(4 + st) * ES + d] + onehot_W[(18 + tox) * ES + d] +
            onehot_W[(26 + sl) * ES + d] + active_W[act * ES + d] + side_W[sd * ES + d];
    } else {                                  // ---- embmm: Eitem / Emoves
        const float* E; const float* W; float* o; int r0;
        if (bid < TB_EM0) { E = item_e;  W = item_W;  o = ws + OFF_EITEM;  r0 = (bid - TB_EI0) * 4; }
        else              { E = moves_e; W = moves_W; o = ws + OFF_EMOVES; r0 = (bid - TB_EM0) * 4; }
        for (int i = d; i < 4 * ES; i += 256)
            se[i >> 8][i & 255] = E[(r0 + (i >> 8)) * ES + (i & 255)];
        __syncthreads();
        int rl = d >> 6, lane = d & 63, d0 = lane * 4;
        float4 acc = make_float4(0.f, 0.f, 0.f, 0.f);
#pragma unroll 4
        for (int k = 0; k < ES; ++k) {
            float e = se[rl][k];
            const float4 w = *reinterpret_cast<const float4*>(&W[k * ES + d0]);
            acc.x += e * w.x; acc.y += e * w.y; acc.z += e * w.z; acc.w += e * w.w;
        }
        *reinterpret_cast<float4*>(&o[(r0 + rl) * ES + d0]) = acc;
    }
}

// ---------------- main gather/accumulate kernel ----------------

__device__ __forceinline__ float4 ld4(const float* p) {
    return *reinterpret_cast<const float4*>(p);
}
__device__ __forceinline__ void add4(float4& a, const float4 b) {
    a.x += b.x; a.y += b.y; a.z += b.z; a.w += b.w;
}
__device__ __forceinline__ void fma4(float4& a, float s, const float4 b) {
    a.x += s * b.x; a.y += s * b.y; a.z += s * b.z; a.w += s * b.w;
}
__device__ __forceinline__ int sclamp(int x, int lo, int hi) {
    return x < lo ? lo : (x > hi ? hi : x);
}

__global__ __launch_bounds__(256) void k_main(
    const int* __restrict__ ent,
    const float* __restrict__ spW, const float* __restrict__ abW,
    const float* __restrict__ onehotW, const float* __restrict__ boostsW,
    const float* __restrict__ ws,
    float* __restrict__ out) {
    int lane = threadIdx.x & 63;
    int wid  = (blockIdx.x * 256 + threadIdx.x) >> 6;       // one wave per entity
    int went = __builtin_amdgcn_readfirstlane(wid);          // wave-uniform entity id
    int d0 = lane * 4;

    // ONE lane-distributed feature load; all 64 lanes active (grid is exact).
    int fv = ent[went * NFEAT + (lane < NFEAT ? lane : 0)];
#define RL(i) __builtin_amdgcn_readlane(fv, (i))

    const float* Hp     = ws + OFF_HP;
    const float* Lv     = ws + OFF_LV;
    const float* Pp     = ws + OFF_PP;
    const float* VP     = ws + OFF_VP;
    const float* CA     = ws + OFF_CA;
    const float* CB     = ws + OFF_CB;
    const float* Eitem  = ws + OFF_EITEM;
    const float* Emoves = ws + OFF_EMOVES;

    // combB (status,toxic,sleep,active,side) + all biases — always valid
    int idxB = ((((RL(F_STATUS) & 7) * 8 + (RL(F_TOXIC) & 7)) * 4 + (RL(F_SLEEP) & 3)) * 2 +
                (RL(F_ACTIVE) & 1)) * 2 + (RL(F_SIDE) & 1);
    float4 acc = ld4(CB + idxB * ES + d0);

    // combA (item_effect,gender,bcb,trapped,newly_switched,fainted)
    int g = sclamp(RL(F_GENDER), 0, 2);
    int idxA = (((((RL(F_ITEM_EFFECT) & 15) * 3 + g) * 2 + (RL(F_BCB) & 1)) * 2 +
                 (RL(F_TRAPPED) & 1)) * 2 + (RL(F_NEWSW) & 1)) * 2 + (RL(F_FAINTED) & 1);
    add4(acc, ld4(CA + idxA * ES + d0));

    // species / ability / item-embedding rows (scalar indices)
    add4(acc, ld4(spW    + sclamp(RL(F_SPECIES), 0, 1025) * ES + d0));
    add4(acc, ld4(abW    + sclamp(RL(F_ABILITY), 0, 299)  * ES + d0));
    add4(acc, ld4(Eitem  + sclamp(RL(F_ITEM),    0, 499)  * ES + d0));

    // hp token + hp_ratio * onehot_W[0]
    {
        float hp = (float)RL(F_HP);
        int mh = RL(F_MAXHP); if (mh < 1) mh = 1;
        float ratio = fminf(fmaxf(hp / (float)mh, 0.f), 1.f);
        int tok = __builtin_amdgcn_readfirstlane((int)floorf(1023.f * ratio));
        add4(acc, ld4(Hp + tok * ES + d0));
        fma4(acc, ratio, ld4(onehotW + d0));
    }

    // level bits
    add4(acc, ld4(Lv + (RL(F_LEVEL) & 127) * ES + d0));

    // boosts (scaled rows); scalar condition -> uniform branch
#pragma unroll
    for (int k = 0; k < 7; ++k) {
        int bv = RL(F_BOOST0 + k);
        if (bv != 0) fma4(acc, 0.5f * (float)bv, ld4(boostsW + k * ES + d0));
    }

    // volatiles via pair tables (k=0..5) + single (k=6)
#pragma unroll
    for (int t = 0; t < 3; ++t) {
        int pair = ((RL(F_VOL0 + 2 * t) & 15) << 4) | (RL(F_VOL0 + 2 * t + 1) & 15);
        if (pair != 0) add4(acc, ld4(VP + (t * 256 + pair) * ES + d0));
    }
    {
        int nib = RL(F_VOL0 + 6) & 15;
        if (nib != 0) add4(acc, ld4(VP + (768 + nib) * ES + d0));
    }

    // moves: 4 x (E_moves[id] + Pp[pp&63])
#pragma unroll
    for (int m = 0; m < 4; ++m) {
        add4(acc, ld4(Emoves + sclamp(RL(F_MOVEID0 + m), 0, 919) * ES + d0));
        int pp = RL(F_MOVEPP0 + m) & 63;
        if (pp != 0) add4(acc, ld4(Pp + pp * ES + d0));
    }
#undef RL

    *reinterpret_cast<float4*>(&out[went * ES + d0]) = acc;
}

// ---------------- host launch ----------------

extern "C" void kernel_launch(void* const* d_in, const int* in_sizes, int n_in,
                              void* d_out, int out_size, void* d_ws, size_t ws_size,
                              hipStream_t stream) {
    const int*   entities = (const int*)  d_in[0];
    const float* sp       = (const float*)d_in[1];
    const float* ab       = (const float*)d_in[2];
    const float* item_e   = (const float*)d_in[3];
    const float* moves_e  = (const float*)d_in[4];
    const float* hp_W     = (const float*)d_in[5];
    const float* hp_b     = (const float*)d_in[6];
    const float* level_W  = (const float*)d_in[7];
    const float* level_b  = (const float*)d_in[8];
    const float* active_W = (const float*)d_in[9];
    const float* active_b = (const float*)d_in[10];
    const float* onehot_W = (const float*)d_in[11];
    const float* onehot_b = (const float*)d_in[12];
    const float* boosts_W = (const float*)d_in[13];
    const float* boosts_b = (const float*)d_in[14];
    const float* vol_W    = (const float*)d_in[15];
    const float* vol_b    = (const float*)d_in[16];
    const float* item_W   = (const float*)d_in[17];
    const float* item_b   = (const float*)d_in[18];
    const float* side_W   = (const float*)d_in[19];
    const float* side_b   = (const float*)d_in[20];
    const float* moves_W  = (const float*)d_in[21];
    const float* moves_b  = (const float*)d_in[22];

    float* ws  = (float*)d_ws;
    float* out = (float*)d_out;

    // ---- single fused precompute dispatch (weight-derived tables) ----
    k_tables<<<TB_TOT, 256, 0, stream>>>(item_e, moves_e, hp_W, level_W, moves_W, vol_W,
                                         item_W, onehot_W, active_W, side_W,
                                         hp_b, level_b, active_b, onehot_b, boosts_b,
                                         vol_b, item_b, side_b, moves_b, ws);

    // ---- main gather kernel: one wave per entity, 4 entities per block ----
    k_main<<<NENT / 4, 256, 0, stream>>>(entities, sp, ab, onehot_W, boosts_W, ws, out);
}

// Round 5
// 251.279 us; speedup vs baseline: 1.3493x; 1.0366x over previous
//
#include <hip/hip_runtime.h>

// ---------------- problem constants (match reference) ----------------
#define ES 256
#define NFEAT 42
#define NENT (8192 * 12)   // 98304 entities

// feature indices
#define F_SPECIES 0
#define F_ABILITY 1
#define F_ITEM 2
#define F_ITEM_EFFECT 3
#define F_GENDER 4
#define F_STATUS 5
#define F_BCB 6
#define F_TRAPPED 7
#define F_NEWSW 8
#define F_TOXIC 9
#define F_SLEEP 10
#define F_FAINTED 11
#define F_ACTIVE 12
#define F_SIDE 13
#define F_LEVEL 14
#define F_HP 15
#define F_MAXHP 16
#define F_BOOST0 17   // 7 boosts: 17..23
#define F_VOL0 24     // 9 vols: 24..32 (only first 7 matter after [:105] truncation)
#define F_MOVEID0 33  // 4 move ids
#define F_MOVEPP0 37  // 4 move pp

// ---------------- workspace layout (floats) ----------------
#define OFF_HP     0                        // 1024 rows
#define OFF_LV     (OFF_HP + 1024*ES)       //  128 rows
#define OFF_PP     (OFF_LV + 128*ES)        //   64 rows (row0 = 0)
#define OFF_VP     (OFF_PP + 64*ES)         //  784 rows (row0 of each subtable = 0)
#define OFF_CA     (OFF_VP + 784*ES)        //  768 rows
#define OFF_CB     (OFF_CA + 768*ES)        // 1024 rows (+ all biases)
#define OFF_EITEM  (OFF_CB + 1024*ES)       //  500 rows
#define OFF_EMOVES (OFF_EITEM + 500*ES)     //  920 rows

// ---------------- helpers ----------------
typedef float vf4 __attribute__((ext_vector_type(4)));

__device__ __forceinline__ float4 ld4(const float* p) {
    return *reinterpret_cast<const float4*>(p);
}
__device__ __forceinline__ void st4(float* p, const float4 v) {
    *reinterpret_cast<float4*>(p) = v;
}
__device__ __forceinline__ void st4_nt(float* p, const float4 v) {
    vf4 t = {v.x, v.y, v.z, v.w};
    __builtin_nontemporal_store(t, reinterpret_cast<vf4*>(p));
}
__device__ __forceinline__ void add4(float4& a, const float4 b) {
    a.x += b.x; a.y += b.y; a.z += b.z; a.w += b.w;
}
__device__ __forceinline__ float4 sum4(const float4 a, const float4 b) {
    return make_float4(a.x + b.x, a.y + b.y, a.z + b.z, a.w + b.w);
}
__device__ __forceinline__ void fma4(float4& a, float s, const float4 b) {
    a.x += s * b.x; a.y += s * b.y; a.z += s * b.z; a.w += s * b.w;
}
__device__ __forceinline__ int sclamp(int x, int lo, int hi) {
    return x < lo ? lo : (x > hi ? hi : x);
}

// ---------------- fused precompute kernel (float4 per thread) ----------------
// Non-MM blocks: 4 rows/block; thread = (rl = tid>>6, lane = tid&63), d0 = lane*4.
#define TB_HP0 0        //  256 blocks: Hp (10-bit bit-sum of hp_W)
#define TB_LV0 256      //   32 blocks: Lv (7-bit bit-sum of level_W)
#define TB_PP0 288      //   16 blocks: Pp (6-bit bit-sum of moves_W[256:262])
#define TB_VP0 304      //  196 blocks: volatile nibble-pair tables
#define TB_CA0 500      //  192 blocks: combA
#define TB_CB0 692      //  256 blocks: combB (+ all biases)
#define TB_EI0 948      //  125 blocks: Eitem = embed_item @ item_W[:256]
#define TB_EM0 1073     //  230 blocks: Emoves = embed_moves @ moves_W[:256]
#define TB_TOT 1303

__global__ __launch_bounds__(256) void k_tables(
    const float* __restrict__ item_e, const float* __restrict__ moves_e,
    const float* __restrict__ hp_W, const float* __restrict__ level_W,
    const float* __restrict__ moves_W, const float* __restrict__ vol_W,
    const float* __restrict__ item_W, const float* __restrict__ onehot_W,
    const float* __restrict__ active_W, const float* __restrict__ side_W,
    const float* __restrict__ hp_b, const float* __restrict__ level_b,
    const float* __restrict__ active_b, const float* __restrict__ onehot_b,
    const float* __restrict__ boosts_b, const float* __restrict__ vol_b,
    const float* __restrict__ item_b, const float* __restrict__ side_b,
    const float* __restrict__ moves_b,
    float* __restrict__ ws) {
    __shared__ float4 se4[4][64];
    const int bid = blockIdx.x, tid = threadIdx.x;
    const int rl = tid >> 6, lane = tid & 63, d0 = lane * 4;
    float4 acc = make_float4(0.f, 0.f, 0.f, 0.f);

    if (bid < TB_LV0) {                       // ---- Hp
        int v = (bid - TB_HP0) * 4 + rl;
        for (int b = 0; b < 10; ++b)
            if ((v >> b) & 1) add4(acc, ld4(hp_W + b * ES + d0));
        st4(ws + OFF_HP + v * ES + d0, acc);
    } else if (bid < TB_PP0) {                // ---- Lv
        int v = (bid - TB_LV0) * 4 + rl;
        for (int b = 0; b < 7; ++b)
            if ((v >> b) & 1) add4(acc, ld4(level_W + b * ES + d0));
        st4(ws + OFF_LV + v * ES + d0, acc);
    } else if (bid < TB_VP0) {                // ---- Pp
        int v = (bid - TB_PP0) * 4 + rl;
        for (int b = 0; b < 6; ++b)
            if ((v >> b) & 1) add4(acc, ld4(moves_W + (256 + b) * ES + d0));
        st4(ws + OFF_PP + v * ES + d0, acc);
    } else if (bid < TB_CA0) {                // ---- VP nibble pairs + single
        int v = (bid - TB_VP0) * 4 + rl;
        if (v < 768) {
            int t = v >> 8, pair = v & 255, a = pair >> 4, b = pair & 15;
            for (int j = 0; j < 16; ++j) {
                if (a & j) add4(acc, ld4(vol_W + (32 * t + j) * ES + d0));
                if (b & j) add4(acc, ld4(vol_W + (32 * t + 16 + j) * ES + d0));
            }
        } else {
            int a = v - 768;
            for (int j = 0; j < 9; ++j)       // rows 96..104 (< 105 truncation)
                if (a & j) add4(acc, ld4(vol_W + (96 + j) * ES + d0));
        }
        st4(ws + OFF_VP + v * ES + d0, acc);
    } else if (bid < TB_CB0) {                // ---- combA
        int idx = (bid - TB_CA0) * 4 + rl;
        int fa = idx & 1, ns = (idx >> 1) & 1, tr = (idx >> 2) & 1, bcb = (idx >> 3) & 1;
        int rest = idx >> 4, g = rest % 3, e = rest / 3;
        acc = sum4(sum4(ld4(item_W + (256 + e) * ES + d0), ld4(onehot_W + (1 + g) * ES + d0)),
                   sum4(ld4(onehot_W + (12 + bcb) * ES + d0), ld4(onehot_W + (14 + tr) * ES + d0)));
        add4(acc, sum4(ld4(onehot_W + (16 + ns) * ES + d0), ld4(onehot_W + (30 + fa) * ES + d0)));
        st4(ws + OFF_CA + idx * ES + d0, acc);
    } else if (bid < TB_EI0) {                // ---- combB (+ all biases)
        int idx = (bid - TB_CB0) * 4 + rl;
        int sd = idx & 1, act = (idx >> 1) & 1, sl = (idx >> 2) & 3,
            tox = (idx >> 4) & 7, st = idx >> 7;
        acc = sum4(sum4(ld4(hp_b + d0), ld4(level_b + d0)),
                   sum4(ld4(active_b + d0), ld4(onehot_b + d0)));
        add4(acc, sum4(ld4(boosts_b + d0), ld4(vol_b + d0)));
        add4(acc, sum4(ld4(item_b + d0), ld4(side_b + d0)));
        fma4(acc, 4.0f, ld4(moves_b + d0));
        add4(acc, sum4(ld4(onehot_W + (4 + st) * ES + d0), ld4(onehot_W + (18 + tox) * ES + d0)));
        add4(acc, sum4(ld4(onehot_W + (26 + sl) * ES + d0),
                       sum4(ld4(active_W + act * ES + d0), ld4(side_W + sd * ES + d0))));
        st4(ws + OFF_CB + idx * ES + d0, acc);
    } else {                                  // ---- embmm: Eitem / Emoves
        const float* E; const float* W; float* o; int r0;
        if (bid < TB_EM0) { E = item_e;  W = item_W;  o = ws + OFF_EITEM;  r0 = (bid - TB_EI0) * 4; }
        else              { E = moves_e; W = moves_W; o = ws + OFF_EMOVES; r0 = (bid - TB_EM0) * 4; }
        se4[tid >> 6][tid & 63] = ld4(E + r0 * ES + tid * 4);   // 4 rows staged as float4
        __syncthreads();
#pragma unroll 4
        for (int k0 = 0; k0 < 64; ++k0) {
            float4 e4 = se4[rl][k0];
            fma4(acc, e4.x, ld4(W + (4 * k0 + 0) * ES + d0));
            fma4(acc, e4.y, ld4(W + (4 * k0 + 1) * ES + d0));
            fma4(acc, e4.z, ld4(W + (4 * k0 + 2) * ES + d0));
            fma4(acc, e4.w, ld4(W + (4 * k0 + 3) * ES + d0));
        }
        st4(o + (r0 + rl) * ES + d0, acc);
    }
}

// ---------------- main gather/accumulate kernel (straight-line) ----------------

__global__ __launch_bounds__(256) void k_main(
    const int* __restrict__ ent,
    const float* __restrict__ spW, const float* __restrict__ abW,
    const float* __restrict__ onehotW, const float* __restrict__ boostsW,
    const float* __restrict__ ws,
    float* __restrict__ out) {
    const int lane = threadIdx.x & 63;
    const int went = __builtin_amdgcn_readfirstlane((blockIdx.x * 256 + threadIdx.x) >> 6);
    const int d0 = lane * 4;

    // ONE lane-distributed feature load; indices extracted via readlane (SGPR).
    int fv = ent[went * NFEAT + (lane < NFEAT ? lane : 0)];
#define RL(i) __builtin_amdgcn_readlane(fv, (i))

    const float* Hp     = ws + OFF_HP;
    const float* Lv     = ws + OFF_LV;
    const float* Pp     = ws + OFF_PP;
    const float* VP     = ws + OFF_VP;
    const float* CA     = ws + OFF_CA;
    const float* CB     = ws + OFF_CB;
    const float* Eitem  = ws + OFF_EITEM;
    const float* Emoves = ws + OFF_EMOVES;

    // ---- all indices up front (SALU) ----
    const int iB = ((((RL(F_STATUS) & 7) * 8 + (RL(F_TOXIC) & 7)) * 4 + (RL(F_SLEEP) & 3)) * 2 +
                    (RL(F_ACTIVE) & 1)) * 2 + (RL(F_SIDE) & 1);
    const int iA = (((((RL(F_ITEM_EFFECT) & 15) * 3 + sclamp(RL(F_GENDER), 0, 2)) * 2 +
                      (RL(F_BCB) & 1)) * 2 + (RL(F_TRAPPED) & 1)) * 2 +
                    (RL(F_NEWSW) & 1)) * 2 + (RL(F_FAINTED) & 1);
    const int iSP = sclamp(RL(F_SPECIES), 0, 1025);
    const int iAB = sclamp(RL(F_ABILITY), 0, 299);
    const int iIT = sclamp(RL(F_ITEM), 0, 499);
    const float hp = (float)RL(F_HP);
    int mh = RL(F_MAXHP); if (mh < 1) mh = 1;
    const float ratio = fminf(fmaxf(hp / (float)mh, 0.f), 1.f);
    const int tok = __builtin_amdgcn_readfirstlane((int)floorf(1023.f * ratio));
    const int iLV = RL(F_LEVEL) & 127;
    const int b0 = RL(F_BOOST0 + 0), b1 = RL(F_BOOST0 + 1), b2 = RL(F_BOOST0 + 2),
              b3 = RL(F_BOOST0 + 3), b4 = RL(F_BOOST0 + 4), b5 = RL(F_BOOST0 + 5),
              b6 = RL(F_BOOST0 + 6);
    const int vp0 = ((RL(F_VOL0 + 0) & 15) << 4) | (RL(F_VOL0 + 1) & 15);
    const int vp1 = ((RL(F_VOL0 + 2) & 15) << 4) | (RL(F_VOL0 + 3) & 15);
    const int vp2 = ((RL(F_VOL0 + 4) & 15) << 4) | (RL(F_VOL0 + 5) & 15);
    const int v6  = RL(F_VOL0 + 6) & 15;
    const int m0 = sclamp(RL(F_MOVEID0 + 0), 0, 919), m1 = sclamp(RL(F_MOVEID0 + 1), 0, 919),
              m2 = sclamp(RL(F_MOVEID0 + 2), 0, 919), m3 = sclamp(RL(F_MOVEID0 + 3), 0, 919);
    const int p0 = RL(F_MOVEPP0 + 0) & 63, p1 = RL(F_MOVEPP0 + 1) & 63,
              p2 = RL(F_MOVEPP0 + 2) & 63, p3 = RL(F_MOVEPP0 + 3) & 63;
#undef RL

    // ---- all gathers issued as one independent batch (row0 of Pp/VP == 0) ----
    const float4 xCB  = ld4(CB + iB * ES + d0);
    const float4 xCA  = ld4(CA + iA * ES + d0);
    const float4 xSP  = ld4(spW + iSP * ES + d0);
    const float4 xAB  = ld4(abW + iAB * ES + d0);
    const float4 xIT  = ld4(Eitem + iIT * ES + d0);
    const float4 xHP  = ld4(Hp + tok * ES + d0);
    const float4 xOH  = ld4(onehotW + d0);
    const float4 xLV  = ld4(Lv + iLV * ES + d0);
    const float4 xV0  = ld4(VP + (0 * 256 + vp0) * ES + d0);
    const float4 xV1  = ld4(VP + (1 * 256 + vp1) * ES + d0);
    const float4 xV2  = ld4(VP + (2 * 256 + vp2) * ES + d0);
    const float4 xV6  = ld4(VP + (768 + v6) * ES + d0);
    const float4 xE0  = ld4(Emoves + m0 * ES + d0);
    const float4 xE1  = ld4(Emoves + m1 * ES + d0);
    const float4 xE2  = ld4(Emoves + m2 * ES + d0);
    const float4 xE3  = ld4(Emoves + m3 * ES + d0);
    const float4 xP0  = ld4(Pp + p0 * ES + d0);
    const float4 xP1  = ld4(Pp + p1 * ES + d0);
    const float4 xP2  = ld4(Pp + p2 * ES + d0);
    const float4 xP3  = ld4(Pp + p3 * ES + d0);
    const float4 xB0  = ld4(boostsW + 0 * ES + d0);
    const float4 xB1  = ld4(boostsW + 1 * ES + d0);
    const float4 xB2  = ld4(boostsW + 2 * ES + d0);
    const float4 xB3  = ld4(boostsW + 3 * ES + d0);
    const float4 xB4  = ld4(boostsW + 4 * ES + d0);
    const float4 xB5  = ld4(boostsW + 5 * ES + d0);
    const float4 xB6  = ld4(boostsW + 6 * ES + d0);

    // ---- tree combine ----
    float4 s0 = sum4(sum4(xCB, xCA), sum4(xSP, xAB));
    float4 s1 = sum4(sum4(xIT, xHP), sum4(xLV, xV6));
    float4 s2 = sum4(sum4(xV0, xV1), sum4(xV2, xE0));
    float4 s3 = sum4(sum4(xE1, xE2), sum4(xE3, xP0));
    float4 s4 = sum4(sum4(xP1, xP2), xP3);
    float4 acc = sum4(sum4(s0, s1), sum4(s2, s3));
    add4(acc, s4);
    fma4(acc, ratio, xOH);
    fma4(acc, 0.5f * (float)b0, xB0);
    fma4(acc, 0.5f * (float)b1, xB1);
    fma4(acc, 0.5f * (float)b2, xB2);
    fma4(acc, 0.5f * (float)b3, xB3);
    fma4(acc, 0.5f * (float)b4, xB4);
    fma4(acc, 0.5f * (float)b5, xB5);
    fma4(acc, 0.5f * (float)b6, xB6);

    // streaming output: non-temporal store keeps gather tables L2-resident
    st4_nt(out + went * ES + d0, acc);
}

// ---------------- host launch ----------------

extern "C" void kernel_launch(void* const* d_in, const int* in_sizes, int n_in,
                              void* d_out, int out_size, void* d_ws, size_t ws_size,
                              hipStream_t stream) {
    const int*   entities = (const int*)  d_in[0];
    const float* sp       = (const float*)d_in[1];
    const float* ab       = (const float*)d_in[2];
    const float* item_e   = (const float*)d_in[3];
    const float* moves_e  = (const float*)d_in[4];
    const float* hp_W     = (const float*)d_in[5];
    const float* hp_b     = (const float*)d_in[6];
    const float* level_W  = (const float*)d_in[7];
    const float* level_b  = (const float*)d_in[8];
    const float* active_W = (const float*)d_in[9];
    const float* active_b = (const float*)d_in[10];
    const float* onehot_W = (const float*)d_in[11];
    const float* onehot_b = (const float*)d_in[12];
    const float* boosts_W = (const float*)d_in[13];
    const float* boosts_b = (const float*)d_in[14];
    const float* vol_W    = (const float*)d_in[15];
    const float* vol_b    = (const float*)d_in[16];
    const float* item_W   = (const float*)d_in[17];
    const float* item_b   = (const float*)d_in[18];
    const float* side_W   = (const float*)d_in[19];
    const float* side_b   = (const float*)d_in[20];
    const float* moves_W  = (const float*)d_in[21];
    const float* moves_b  = (const float*)d_in[22];

    float* ws  = (float*)d_ws;
    float* out = (float*)d_out;

    // ---- single fused precompute dispatch (weight-derived tables) ----
    k_tables<<<TB_TOT, 256, 0, stream>>>(item_e, moves_e, hp_W, level_W, moves_W, vol_W,
                                         item_W, onehot_W, active_W, side_W,
                                         hp_b, level_b, active_b, onehot_b, boosts_b,
                                         vol_b, item_b, side_b, moves_b, ws);

    // ---- main gather kernel: one wave per entity, 4 entities per block ----
    k_main<<<NENT / 4, 256, 0, stream>>>(entities, sp, ab, onehot_W, boosts_W, ws, out);
}

// Round 6
// 233.621 us; speedup vs baseline: 1.4512x; 1.0756x over previous
//
#include <hip/hip_runtime.h>

// ---------------- problem constants (match reference) ----------------
#define ES 256
#define NFEAT 42
#define NENT (8192 * 12)   // 98304 entities

// feature indices
#define F_SPECIES 0
#define F_ABILITY 1
#define F_ITEM 2
#define F_ITEM_EFFECT 3
#define F_GENDER 4
#define F_STATUS 5
#define F_BCB 6
#define F_TRAPPED 7
#define F_NEWSW 8
#define F_TOXIC 9
#define F_SLEEP 10
#define F_FAINTED 11
#define F_ACTIVE 12
#define F_SIDE 13
#define F_LEVEL 14
#define F_HP 15
#define F_MAXHP 16
#define F_BOOST0 17   // 7 boosts: 17..23
#define F_VOL0 24     // 9 vols: 24..32 (only first 7 matter after [:105] truncation)
#define F_MOVEID0 33  // 4 move ids
#define F_MOVEPP0 37  // 4 move pp

// ---------------- workspace layout (floats) ----------------
#define OFF_HP     0                        // 1024 rows (10-bit hp-token)
#define OFF_LV     (OFF_HP + 1024*ES)       //  128 rows (7-bit level)
#define OFF_PP     (OFF_LV + 128*ES)        //   64 rows (fallback path only)
#define OFF_VP     (OFF_PP + 64*ES)         //  784 rows (vol pair subtbl 0,1,2 + v6 single)
#define OFF_CA     (OFF_VP + 784*ES)        //  768 rows
#define OFF_CB     (OFF_CA + 768*ES)        // 1024 rows (+ all biases)
#define OFF_EITEM  (OFF_CB + 1024*ES)       //  500 rows
#define OFF_EMOVES (OFF_EITEM + 500*ES)     //  920 rows
#define OFF_PPP    (OFF_EMOVES + 920*ES)    // 4096 rows: Pp[a]+Pp[b], idx=(a<<6)|b
#define OFF_VQ     (OFF_PPP + 4096*ES)      // 4096 rows: vols 4,5,6 merged, idx=(v4<<8)|(v5<<4)|v6
#define WS_FLOATS  (OFF_VQ + 4096*ES)       // 13404 rows ~ 13.7 MB

// ---------------- helpers ----------------
typedef float vf4 __attribute__((ext_vector_type(4)));

__device__ __forceinline__ float4 ld4(const float* p) {
    return *reinterpret_cast<const float4*>(p);
}
__device__ __forceinline__ void st4(float* p, const float4 v) {
    *reinterpret_cast<float4*>(p) = v;
}
__device__ __forceinline__ void st4_nt(float* p, const float4 v) {
    vf4 t = {v.x, v.y, v.z, v.w};
    __builtin_nontemporal_store(t, reinterpret_cast<vf4*>(p));
}
__device__ __forceinline__ void add4(float4& a, const float4 b) {
    a.x += b.x; a.y += b.y; a.z += b.z; a.w += b.w;
}
__device__ __forceinline__ float4 sum4(const float4 a, const float4 b) {
    return make_float4(a.x + b.x, a.y + b.y, a.z + b.z, a.w + b.w);
}
__device__ __forceinline__ void fma4(float4& a, float s, const float4 b) {
    a.x += s * b.x; a.y += s * b.y; a.z += s * b.z; a.w += s * b.w;
}
__device__ __forceinline__ int sclamp(int x, int lo, int hi) {
    return x < lo ? lo : (x > hi ? hi : x);
}

// ---------------- fused precompute kernel (float4/thread, 4 rows/block) ----------------
#define TB_HP0  0       //  256 blocks
#define TB_LV0  256     //   32 blocks
#define TB_PP0  288     //   16 blocks
#define TB_VP0  304     //  196 blocks
#define TB_CA0  500     //  192 blocks
#define TB_CB0  692     //  256 blocks
#define TB_EI0  948     //  125 blocks
#define TB_EM0  1073    //  230 blocks
#define TB_BASE 1303
#define TB_PPP0 1303    // 1024 blocks (4096 rows)
#define TB_VQ0  2327    // 1024 blocks (4096 rows)
#define TB_FULL 3351

__global__ __launch_bounds__(256) void k_tables(
    const float* __restrict__ item_e, const float* __restrict__ moves_e,
    const float* __restrict__ hp_W, const float* __restrict__ level_W,
    const float* __restrict__ moves_W, const float* __restrict__ vol_W,
    const float* __restrict__ item_W, const float* __restrict__ onehot_W,
    const float* __restrict__ active_W, const float* __restrict__ side_W,
    const float* __restrict__ hp_b, const float* __restrict__ level_b,
    const float* __restrict__ active_b, const float* __restrict__ onehot_b,
    const float* __restrict__ boosts_b, const float* __restrict__ vol_b,
    const float* __restrict__ item_b, const float* __restrict__ side_b,
    const float* __restrict__ moves_b,
    float* __restrict__ ws) {
    __shared__ float4 se4[4][64];
    const int bid = blockIdx.x, tid = threadIdx.x;
    const int rl = tid >> 6, lane = tid & 63, d0 = lane * 4;
    float4 acc = make_float4(0.f, 0.f, 0.f, 0.f);

    if (bid < TB_LV0) {                       // ---- Hp
        int v = (bid - TB_HP0) * 4 + rl;
        for (int b = 0; b < 10; ++b)
            if ((v >> b) & 1) add4(acc, ld4(hp_W + b * ES + d0));
        st4(ws + OFF_HP + v * ES + d0, acc);
    } else if (bid < TB_PP0) {                // ---- Lv
        int v = (bid - TB_LV0) * 4 + rl;
        for (int b = 0; b < 7; ++b)
            if ((v >> b) & 1) add4(acc, ld4(level_W + b * ES + d0));
        st4(ws + OFF_LV + v * ES + d0, acc);
    } else if (bid < TB_VP0) {                // ---- Pp (fallback path)
        int v = (bid - TB_PP0) * 4 + rl;
        for (int b = 0; b < 6; ++b)
            if ((v >> b) & 1) add4(acc, ld4(moves_W + (256 + b) * ES + d0));
        st4(ws + OFF_PP + v * ES + d0, acc);
    } else if (bid < TB_CA0) {                // ---- VP nibble pairs + v6 single
        int v = (bid - TB_VP0) * 4 + rl;
        if (v < 768) {
            int t = v >> 8, pair = v & 255, a = pair >> 4, b = pair & 15;
            for (int j = 0; j < 16; ++j) {
                if (a & j) add4(acc, ld4(vol_W + (32 * t + j) * ES + d0));
                if (b & j) add4(acc, ld4(vol_W + (32 * t + 16 + j) * ES + d0));
            }
        } else {
            int a = v - 768;
            for (int j = 0; j < 9; ++j)       // rows 96..104 (< 105 truncation)
                if (a & j) add4(acc, ld4(vol_W + (96 + j) * ES + d0));
        }
        st4(ws + OFF_VP + v * ES + d0, acc);
    } else if (bid < TB_CB0) {                // ---- combA
        int idx = (bid - TB_CA0) * 4 + rl;
        int fa = idx & 1, ns = (idx >> 1) & 1, tr = (idx >> 2) & 1, bcb = (idx >> 3) & 1;
        int rest = idx >> 4, g = rest % 3, e = rest / 3;
        acc = sum4(sum4(ld4(item_W + (256 + e) * ES + d0), ld4(onehot_W + (1 + g) * ES + d0)),
                   sum4(ld4(onehot_W + (12 + bcb) * ES + d0), ld4(onehot_W + (14 + tr) * ES + d0)));
        add4(acc, sum4(ld4(onehot_W + (16 + ns) * ES + d0), ld4(onehot_W + (30 + fa) * ES + d0)));
        st4(ws + OFF_CA + idx * ES + d0, acc);
    } else if (bid < TB_EI0) {                // ---- combB (+ all biases)
        int idx = (bid - TB_CB0) * 4 + rl;
        int sd = idx & 1, act = (idx >> 1) & 1, sl = (idx >> 2) & 3,
            tox = (idx >> 4) & 7, st = idx >> 7;
        acc = sum4(sum4(ld4(hp_b + d0), ld4(level_b + d0)),
                   sum4(ld4(active_b + d0), ld4(onehot_b + d0)));
        add4(acc, sum4(ld4(boosts_b + d0), ld4(vol_b + d0)));
        add4(acc, sum4(ld4(item_b + d0), ld4(side_b + d0)));
        fma4(acc, 4.0f, ld4(moves_b + d0));
        add4(acc, sum4(ld4(onehot_W + (4 + st) * ES + d0), ld4(onehot_W + (18 + tox) * ES + d0)));
        add4(acc, sum4(ld4(onehot_W + (26 + sl) * ES + d0),
                       sum4(ld4(active_W + act * ES + d0), ld4(side_W + sd * ES + d0))));
        st4(ws + OFF_CB + idx * ES + d0, acc);
    } else if (bid < TB_PPP0) {               // ---- embmm: Eitem / Emoves
        const float* E; const float* W; float* o; int r0;
        if (bid < TB_EM0) { E = item_e;  W = item_W;  o = ws + OFF_EITEM;  r0 = (bid - TB_EI0) * 4; }
        else              { E = moves_e; W = moves_W; o = ws + OFF_EMOVES; r0 = (bid - TB_EM0) * 4; }
        se4[tid >> 6][tid & 63] = ld4(E + r0 * ES + tid * 4);   // 4 rows staged as float4
        __syncthreads();
#pragma unroll 4
        for (int k0 = 0; k0 < 64; ++k0) {
            float4 e4 = se4[rl][k0];
            fma4(acc, e4.x, ld4(W + (4 * k0 + 0) * ES + d0));
            fma4(acc, e4.y, ld4(W + (4 * k0 + 1) * ES + d0));
            fma4(acc, e4.z, ld4(W + (4 * k0 + 2) * ES + d0));
            fma4(acc, e4.w, ld4(W + (4 * k0 + 3) * ES + d0));
        }
        st4(o + (r0 + rl) * ES + d0, acc);
    } else if (bid < TB_VQ0) {                // ---- PPP: pp-pair table
        int v = (bid - TB_PPP0) * 4 + rl;
        int a = v >> 6, b = v & 63;
        for (int j = 0; j < 6; ++j) {
            float c = (float)(((a >> j) & 1) + ((b >> j) & 1));
            fma4(acc, c, ld4(moves_W + (256 + j) * ES + d0));
        }
        st4(ws + OFF_PPP + v * ES + d0, acc);
    } else {                                  // ---- VQ: vols 4,5,6 merged
        int v = (bid - TB_VQ0) * 4 + rl;
        int a = (v >> 8) & 15, b = (v >> 4) & 15, c = v & 15;
        for (int j = 0; j < 16; ++j) {
            if (a & j) add4(acc, ld4(vol_W + (64 + j) * ES + d0));
            if (b & j) add4(acc, ld4(vol_W + (80 + j) * ES + d0));
            if (j < 9 && (c & j)) add4(acc, ld4(vol_W + (96 + j) * ES + d0));
        }
        st4(ws + OFF_VQ + v * ES + d0, acc);
    }
}

// ---------------- main gather/accumulate kernel ----------------
// 8 fixed rows (7 boostsW + onehot_W row0) staged in LDS; indexed rows gathered.

template <bool MERGED>
__global__ __launch_bounds__(256) void k_main(
    const int* __restrict__ ent,
    const float* __restrict__ spW, const float* __restrict__ abW,
    const float* __restrict__ onehotW, const float* __restrict__ boostsW,
    const float* __restrict__ ws,
    float* __restrict__ out) {
    __shared__ float lds[8 * ES];
    {   // stage: thread t covers floats [t*8, t*8+8)
        int t = threadIdx.x;
        int row = t >> 5, col = (t & 31) * 8;
        const float* src = (row < 7) ? (boostsW + row * ES + col) : (onehotW + col);
        st4(&lds[row * ES + col], ld4(src));
        st4(&lds[row * ES + col + 4], ld4(src + 4));
    }
    __syncthreads();

    const int lane = threadIdx.x & 63;
    const int went = __builtin_amdgcn_readfirstlane((blockIdx.x * 256 + threadIdx.x) >> 6);
    const int d0 = lane * 4;

    int fv = ent[went * NFEAT + (lane < NFEAT ? lane : 0)];
#define RL(i) __builtin_amdgcn_readlane(fv, (i))

    const float* Hp     = ws + OFF_HP;
    const float* Lv     = ws + OFF_LV;
    const float* Pp     = ws + OFF_PP;
    const float* VP     = ws + OFF_VP;
    const float* CA     = ws + OFF_CA;
    const float* CB     = ws + OFF_CB;
    const float* Eitem  = ws + OFF_EITEM;
    const float* Emoves = ws + OFF_EMOVES;
    const float* PPP    = ws + OFF_PPP;
    const float* VQ     = ws + OFF_VQ;

    // ---- indices up front (SALU via readlane) ----
    const int iB = ((((RL(F_STATUS) & 7) * 8 + (RL(F_TOXIC) & 7)) * 4 + (RL(F_SLEEP) & 3)) * 2 +
                    (RL(F_ACTIVE) & 1)) * 2 + (RL(F_SIDE) & 1);
    const int iA = (((((RL(F_ITEM_EFFECT) & 15) * 3 + sclamp(RL(F_GENDER), 0, 2)) * 2 +
                      (RL(F_BCB) & 1)) * 2 + (RL(F_TRAPPED) & 1)) * 2 +
                    (RL(F_NEWSW) & 1)) * 2 + (RL(F_FAINTED) & 1);
    const int iSP = sclamp(RL(F_SPECIES), 0, 1025);
    const int iAB = sclamp(RL(F_ABILITY), 0, 299);
    const int iIT = sclamp(RL(F_ITEM), 0, 499);
    const float hp = (float)RL(F_HP);
    int mh = RL(F_MAXHP); if (mh < 1) mh = 1;
    const float ratio = fminf(fmaxf(hp / (float)mh, 0.f), 1.f);
    const int tok = __builtin_amdgcn_readfirstlane((int)floorf(1023.f * ratio));
    const int iLV = RL(F_LEVEL) & 127;
    const int b0 = RL(F_BOOST0 + 0), b1 = RL(F_BOOST0 + 1), b2 = RL(F_BOOST0 + 2),
              b3 = RL(F_BOOST0 + 3), b4 = RL(F_BOOST0 + 4), b5 = RL(F_BOOST0 + 5),
              b6 = RL(F_BOOST0 + 6);
    const int vp0 = ((RL(F_VOL0 + 0) & 15) << 4) | (RL(F_VOL0 + 1) & 15);
    const int vp1 = ((RL(F_VOL0 + 2) & 15) << 4) | (RL(F_VOL0 + 3) & 15);
    const int vp2 = ((RL(F_VOL0 + 4) & 15) << 4) | (RL(F_VOL0 + 5) & 15);
    const int v6  = RL(F_VOL0 + 6) & 15;
    const int m0 = sclamp(RL(F_MOVEID0 + 0), 0, 919), m1 = sclamp(RL(F_MOVEID0 + 1), 0, 919),
              m2 = sclamp(RL(F_MOVEID0 + 2), 0, 919), m3 = sclamp(RL(F_MOVEID0 + 3), 0, 919);
    const int p0 = RL(F_MOVEPP0 + 0) & 63, p1 = RL(F_MOVEPP0 + 1) & 63,
              p2 = RL(F_MOVEPP0 + 2) & 63, p3 = RL(F_MOVEPP0 + 3) & 63;
#undef RL

    // ---- indexed gathers (batched) ----
    const float4 xCB = ld4(CB + iB * ES + d0);
    const float4 xCA = ld4(CA + iA * ES + d0);
    const float4 xSP = ld4(spW + iSP * ES + d0);
    const float4 xAB = ld4(abW + iAB * ES + d0);
    const float4 xIT = ld4(Eitem + iIT * ES + d0);
    const float4 xHP = ld4(Hp + tok * ES + d0);
    const float4 xLV = ld4(Lv + iLV * ES + d0);
    const float4 xV0 = ld4(VP + (0 * 256 + vp0) * ES + d0);
    const float4 xV1 = ld4(VP + (1 * 256 + vp1) * ES + d0);
    const float4 xE0 = ld4(Emoves + m0 * ES + d0);
    const float4 xE1 = ld4(Emoves + m1 * ES + d0);
    const float4 xE2 = ld4(Emoves + m2 * ES + d0);
    const float4 xE3 = ld4(Emoves + m3 * ES + d0);

    float4 acc;
    if (MERGED) {
        const float4 xVQ = ld4(VQ + ((vp2 << 4) | v6) * ES + d0);
        const float4 xPa = ld4(PPP + ((p0 << 6) | p1) * ES + d0);
        const float4 xPb = ld4(PPP + ((p2 << 6) | p3) * ES + d0);
        float4 s0 = sum4(sum4(xCB, xCA), sum4(xSP, xAB));
        float4 s1 = sum4(sum4(xIT, xHP), sum4(xLV, xVQ));
        float4 s2 = sum4(sum4(xV0, xV1), sum4(xPa, xPb));
        float4 s3 = sum4(sum4(xE0, xE1), sum4(xE2, xE3));
        acc = sum4(sum4(s0, s1), sum4(s2, s3));
    } else {
        const float4 xV2 = ld4(VP + (2 * 256 + vp2) * ES + d0);
        const float4 xV6 = ld4(VP + (768 + v6) * ES + d0);
        const float4 xP0 = ld4(Pp + p0 * ES + d0);
        const float4 xP1 = ld4(Pp + p1 * ES + d0);
        const float4 xP2 = ld4(Pp + p2 * ES + d0);
        const float4 xP3 = ld4(Pp + p3 * ES + d0);
        float4 s0 = sum4(sum4(xCB, xCA), sum4(xSP, xAB));
        float4 s1 = sum4(sum4(xIT, xHP), sum4(xLV, xV6));
        float4 s2 = sum4(sum4(xV0, xV1), sum4(xV2, xP0));
        float4 s3 = sum4(sum4(xE0, xE1), sum4(xE2, xE3));
        float4 s4 = sum4(sum4(xP1, xP2), xP3);
        acc = sum4(sum4(s0, s1), sum4(s2, s3));
        add4(acc, s4);
    }

    // ---- LDS rows: ratio*OH0 + boosts ----
    fma4(acc, ratio, ld4(&lds[7 * ES + d0]));
    fma4(acc, 0.5f * (float)b0, ld4(&lds[0 * ES + d0]));
    fma4(acc, 0.5f * (float)b1, ld4(&lds[1 * ES + d0]));
    fma4(acc, 0.5f * (float)b2, ld4(&lds[2 * ES + d0]));
    fma4(acc, 0.5f * (float)b3, ld4(&lds[3 * ES + d0]));
    fma4(acc, 0.5f * (float)b4, ld4(&lds[4 * ES + d0]));
    fma4(acc, 0.5f * (float)b5, ld4(&lds[5 * ES + d0]));
    fma4(acc, 0.5f * (float)b6, ld4(&lds[6 * ES + d0]));

    st4_nt(out + went * ES + d0, acc);   // streaming store
}

// ---------------- host launch ----------------

extern "C" void kernel_launch(void* const* d_in, const int* in_sizes, int n_in,
                              void* d_out, int out_size, void* d_ws, size_t ws_size,
                              hipStream_t stream) {
    const int*   entities = (const int*)  d_in[0];
    const float* sp       = (const float*)d_in[1];
    const float* ab       = (const float*)d_in[2];
    const float* item_e   = (const float*)d_in[3];
    const float* moves_e  = (const float*)d_in[4];
    const float* hp_W     = (const float*)d_in[5];
    const float* hp_b     = (const float*)d_in[6];
    const float* level_W  = (const float*)d_in[7];
    const float* level_b  = (const float*)d_in[8];
    const float* active_W = (const float*)d_in[9];
    const float* active_b = (const float*)d_in[10];
    const float* onehot_W = (const float*)d_in[11];
    const float* onehot_b = (const float*)d_in[12];
    const float* boosts_W = (const float*)d_in[13];
    const float* boosts_b = (const float*)d_in[14];
    const float* vol_W    = (const float*)d_in[15];
    const float* vol_b    = (const float*)d_in[16];
    const float* item_W   = (const float*)d_in[17];
    const float* item_b   = (const float*)d_in[18];
    const float* side_W   = (const float*)d_in[19];
    const float* side_b   = (const float*)d_in[20];
    const float* moves_W  = (const float*)d_in[21];
    const float* moves_b  = (const float*)d_in[22];

    float* ws  = (float*)d_ws;
    float* out = (float*)d_out;

    const bool merged = ws_size >= (size_t)WS_FLOATS * sizeof(float);

    k_tables<<<merged ? TB_FULL : TB_BASE, 256, 0, stream>>>(
        item_e, moves_e, hp_W, level_W, moves_W, vol_W,
        item_W, onehot_W, active_W, side_W,
        hp_b, level_b, active_b, onehot_b, boosts_b,
        vol_b, item_b, side_b, moves_b, ws);

    if (merged)
        k_main<true><<<NENT / 4, 256, 0, stream>>>(entities, sp, ab, onehot_W, boosts_W, ws, out);
    else
        k_main<false><<<NENT / 4, 256, 0, stream>>>(entities, sp, ab, onehot_W, boosts_W, ws, out);
}

// Round 8
// 232.878 us; speedup vs baseline: 1.4559x; 1.0032x over previous
//
#include <hip/hip_runtime.h>
#include <hip/hip_fp16.h>

// ---------------- problem constants (match reference) ----------------
#define ES 256
#define NFEAT 42
#define NENT (8192 * 12)   // 98304 entities

// feature indices
#define F_SPECIES 0
#define F_ABILITY 1
#define F_ITEM 2
#define F_ITEM_EFFECT 3
#define F_GENDER 4
#define F_STATUS 5
#define F_BCB 6
#define F_TRAPPED 7
#define F_NEWSW 8
#define F_TOXIC 9
#define F_SLEEP 10
#define F_FAINTED 11
#define F_ACTIVE 12
#define F_SIDE 13
#define F_LEVEL 14
#define F_HP 15
#define F_MAXHP 16
#define F_BOOST0 17   // 7 boosts: 17..23
#define F_VOL0 24     // 9 vols: 24..32 (only first 7 matter after [:105] truncation)
#define F_MOVEID0 33  // 4 move ids
#define F_MOVEPP0 37  // 4 move pp

// ---------------- workspace layout (UNITS: halves) — all tables fp16 ----------------
#define OFF_HP     0                        // 1024 rows (10-bit hp-token)
#define OFF_LV     (OFF_HP + 1024*ES)       //  128 rows (7-bit level)
#define OFF_PP     (OFF_LV + 128*ES)        //   64 rows (6-bit movepp; row0 = 0)
#define OFF_VP     (OFF_PP + 64*ES)         //  784 rows (vol pairs t=0,1,2 + v6 single)
#define OFF_CA     (OFF_VP + 784*ES)        //  768 rows
#define OFF_CB     (OFF_CA + 768*ES)        // 1024 rows (+ all biases)
#define OFF_EI     (OFF_CB + 1024*ES)       //  500 rows (embed_item @ item_W[:256])
#define OFF_EM     (OFF_EI + 500*ES)        //  920 rows (embed_moves @ moves_W[:256])
#define OFF_SP     (OFF_EM + 920*ES)        // 1026 rows (fp16 copy of embed_species)
#define OFF_AB     (OFF_SP + 1026*ES)       //  300 rows (fp16 copy of embed_ability)
#define WS_HALVES  (OFF_AB + 300*ES)        // 6538 rows ~ 3.35 MB (fits per-XCD L2)

// ---------------- helpers ----------------
typedef float vf4 __attribute__((ext_vector_type(4)));

__device__ __forceinline__ float4 ld4(const float* p) {
    return *reinterpret_cast<const float4*>(p);
}
__device__ __forceinline__ void st4(float* p, const float4 v) {
    *reinterpret_cast<float4*>(p) = v;
}
__device__ __forceinline__ void st4_nt(float* p, const float4 v) {
    vf4 t = {v.x, v.y, v.z, v.w};
    __builtin_nontemporal_store(t, reinterpret_cast<vf4*>(p));
}
__device__ __forceinline__ void add4(float4& a, const float4 b) {
    a.x += b.x; a.y += b.y; a.z += b.z; a.w += b.w;
}
__device__ __forceinline__ float4 sum4(const float4 a, const float4 b) {
    return make_float4(a.x + b.x, a.y + b.y, a.z + b.z, a.w + b.w);
}
__device__ __forceinline__ void fma4(float4& a, float s, const float4 b) {
    a.x += s * b.x; a.y += s * b.y; a.z += s * b.z; a.w += s * b.w;
}
__device__ __forceinline__ int sclamp(int x, int lo, int hi) {
    return x < lo ? lo : (x > hi ? hi : x);
}
// store 4 floats as 4 halves (8B)
__device__ __forceinline__ void st4h(__half* p, const float4 v) {
    __half2 a = __floats2half2_rn(v.x, v.y);
    __half2 b = __floats2half2_rn(v.z, v.w);
    uint2 u;
    u.x = *reinterpret_cast<unsigned*>(&a);
    u.y = *reinterpret_cast<unsigned*>(&b);
    *reinterpret_cast<uint2*>(p) = u;
}
// gather 4 halves (8B) -> float4
__device__ __forceinline__ float4 ldh4(const __half* p) {
    uint2 u = *reinterpret_cast<const uint2*>(p);
    __half2 a = *reinterpret_cast<__half2*>(&u.x);
    __half2 b = *reinterpret_cast<__half2*>(&u.y);
    float2 fa = __half22float2(a), fb = __half22float2(b);
    return make_float4(fa.x, fa.y, fb.x, fb.y);
}

// ---------------- fused precompute kernel (4 rows/block, fp16 out) ----------------
#define TB_HP0 0        //  256 blocks
#define TB_LV0 256      //   32 blocks
#define TB_PP0 288      //   16 blocks
#define TB_VP0 304      //  196 blocks
#define TB_CA0 500      //  192 blocks
#define TB_CB0 692      //  256 blocks
#define TB_EI0 948      //  125 blocks
#define TB_EM0 1073     //  230 blocks
#define TB_SP0 1303     //  257 blocks (1026 rows, guarded)
#define TB_AB0 1560     //   75 blocks
#define TB_TOT 1635

__global__ __launch_bounds__(256) void k_tables(
    const float* __restrict__ sp_e, const float* __restrict__ ab_e,
    const float* __restrict__ item_e, const float* __restrict__ moves_e,
    const float* __restrict__ hp_W, const float* __restrict__ level_W,
    const float* __restrict__ moves_W, const float* __restrict__ vol_W,
    const float* __restrict__ item_W, const float* __restrict__ onehot_W,
    const float* __restrict__ active_W, const float* __restrict__ side_W,
    const float* __restrict__ hp_b, const float* __restrict__ level_b,
    const float* __restrict__ active_b, const float* __restrict__ onehot_b,
    const float* __restrict__ boosts_b, const float* __restrict__ vol_b,
    const float* __restrict__ item_b, const float* __restrict__ side_b,
    const float* __restrict__ moves_b,
    __half* __restrict__ wh) {
    __shared__ float4 se4[4][64];
    const int bid = blockIdx.x, tid = threadIdx.x;
    const int rl = tid >> 6, lane = tid & 63, d0 = lane * 4;
    float4 acc = make_float4(0.f, 0.f, 0.f, 0.f);

    if (bid < TB_LV0) {                       // ---- Hp
        int v = (bid - TB_HP0) * 4 + rl;
        for (int b = 0; b < 10; ++b)
            if ((v >> b) & 1) add4(acc, ld4(hp_W + b * ES + d0));
        st4h(wh + OFF_HP + v * ES + d0, acc);
    } else if (bid < TB_PP0) {                // ---- Lv
        int v = (bid - TB_LV0) * 4 + rl;
        for (int b = 0; b < 7; ++b)
            if ((v >> b) & 1) add4(acc, ld4(level_W + b * ES + d0));
        st4h(wh + OFF_LV + v * ES + d0, acc);
    } else if (bid < TB_VP0) {                // ---- Pp
        int v = (bid - TB_PP0) * 4 + rl;
        for (int b = 0; b < 6; ++b)
            if ((v >> b) & 1) add4(acc, ld4(moves_W + (256 + b) * ES + d0));
        st4h(wh + OFF_PP + v * ES + d0, acc);
    } else if (bid < TB_CA0) {                // ---- VP nibble pairs + v6 single
        int v = (bid - TB_VP0) * 4 + rl;
        if (v < 768) {
            int t = v >> 8, pair = v & 255, a = pair >> 4, b = pair & 15;
            for (int j = 0; j < 16; ++j) {
                if (a & j) add4(acc, ld4(vol_W + (32 * t + j) * ES + d0));
                if (b & j) add4(acc, ld4(vol_W + (32 * t + 16 + j) * ES + d0));
            }
        } else {
            int a = v - 768;
            for (int j = 0; j < 9; ++j)       // rows 96..104 (< 105 truncation)
                if (a & j) add4(acc, ld4(vol_W + (96 + j) * ES + d0));
        }
        st4h(wh + OFF_VP + v * ES + d0, acc);
    } else if (bid < TB_CB0) {                // ---- combA
        int idx = (bid - TB_CA0) * 4 + rl;
        int fa = idx & 1, ns = (idx >> 1) & 1, tr = (idx >> 2) & 1, bcb = (idx >> 3) & 1;
        int rest = idx >> 4, g = rest % 3, e = rest / 3;
        acc = sum4(sum4(ld4(item_W + (256 + e) * ES + d0), ld4(onehot_W + (1 + g) * ES + d0)),
                   sum4(ld4(onehot_W + (12 + bcb) * ES + d0), ld4(onehot_W + (14 + tr) * ES + d0)));
        add4(acc, sum4(ld4(onehot_W + (16 + ns) * ES + d0), ld4(onehot_W + (30 + fa) * ES + d0)));
        st4h(wh + OFF_CA + idx * ES + d0, acc);
    } else if (bid < TB_EI0) {                // ---- combB (+ all biases)
        int idx = (bid - TB_CB0) * 4 + rl;
        int sd = idx & 1, act = (idx >> 1) & 1, sl = (idx >> 2) & 3,
            tox = (idx >> 4) & 7, st = idx >> 7;
        acc = sum4(sum4(ld4(hp_b + d0), ld4(level_b + d0)),
                   sum4(ld4(active_b + d0), ld4(onehot_b + d0)));
        add4(acc, sum4(ld4(boosts_b + d0), ld4(vol_b + d0)));
        add4(acc, sum4(ld4(item_b + d0), ld4(side_b + d0)));
        fma4(acc, 4.0f, ld4(moves_b + d0));
        add4(acc, sum4(ld4(onehot_W + (4 + st) * ES + d0), ld4(onehot_W + (18 + tox) * ES + d0)));
        add4(acc, sum4(ld4(onehot_W + (26 + sl) * ES + d0),
                       sum4(ld4(active_W + act * ES + d0), ld4(side_W + sd * ES + d0))));
        st4h(wh + OFF_CB + idx * ES + d0, acc);
    } else if (bid < TB_SP0) {                // ---- embmm: Eitem / Emoves
        const float* E; const float* W; __half* o; int r0;
        if (bid < TB_EM0) { E = item_e;  W = item_W;  o = wh + OFF_EI; r0 = (bid - TB_EI0) * 4; }
        else              { E = moves_e; W = moves_W; o = wh + OFF_EM; r0 = (bid - TB_EM0) * 4; }
        se4[tid >> 6][tid & 63] = ld4(E + r0 * ES + tid * 4);   // 4 rows staged
        __syncthreads();
#pragma unroll 4
        for (int k0 = 0; k0 < 64; ++k0) {
            float4 e4 = se4[rl][k0];
            fma4(acc, e4.x, ld4(W + (4 * k0 + 0) * ES + d0));
            fma4(acc, e4.y, ld4(W + (4 * k0 + 1) * ES + d0));
            fma4(acc, e4.z, ld4(W + (4 * k0 + 2) * ES + d0));
            fma4(acc, e4.w, ld4(W + (4 * k0 + 3) * ES + d0));
        }
        st4h(o + (r0 + rl) * ES + d0, acc);
    } else if (bid < TB_AB0) {                // ---- fp16 copy of embed_species
        int r = (bid - TB_SP0) * 4 + rl;
        if (r < 1026) st4h(wh + OFF_SP + r * ES + d0, ld4(sp_e + r * ES + d0));
    } else {                                  // ---- fp16 copy of embed_ability
        int r = (bid - TB_AB0) * 4 + rl;
        st4h(wh + OFF_AB + r * ES + d0, ld4(ab_e + r * ES + d0));
    }
}

// ---------------- main gather/accumulate kernel ----------------
// 19 fp16 gathers (512 B/wave each) + 8 LDS fixed rows + nt entity load/out store.

__global__ __launch_bounds__(256) void k_main(
    const int* __restrict__ ent,
    const float* __restrict__ onehotW, const float* __restrict__ boostsW,
    const __half* __restrict__ wh,
    float* __restrict__ out) {
    __shared__ float lds[8 * ES];
    {   // stage 8 fixed f32 rows: 7 boostsW + onehot_W row0
        int t = threadIdx.x;
        int row = t >> 5, col = (t & 31) * 8;
        const float* src = (row < 7) ? (boostsW + row * ES + col) : (onehotW + col);
        st4(&lds[row * ES + col], ld4(src));
        st4(&lds[row * ES + col + 4], ld4(src + 4));
    }
    __syncthreads();

    const int lane = threadIdx.x & 63;
    const int went = __builtin_amdgcn_readfirstlane((blockIdx.x * 256 + threadIdx.x) >> 6);
    const int d0 = lane * 4;

    int fv = __builtin_nontemporal_load(ent + went * NFEAT + (lane < NFEAT ? lane : 0));
#define RL(i) __builtin_amdgcn_readlane(fv, (i))

    const __half* Hp = wh + OFF_HP;
    const __half* Lv = wh + OFF_LV;
    const __half* Pp = wh + OFF_PP;
    const __half* VP = wh + OFF_VP;
    const __half* CA = wh + OFF_CA;
    const __half* CB = wh + OFF_CB;
    const __half* EI = wh + OFF_EI;
    const __half* EM = wh + OFF_EM;
    const __half* SP = wh + OFF_SP;
    const __half* AB = wh + OFF_AB;

    // ---- indices up front (SALU via readlane) ----
    const int iB = ((((RL(F_STATUS) & 7) * 8 + (RL(F_TOXIC) & 7)) * 4 + (RL(F_SLEEP) & 3)) * 2 +
                    (RL(F_ACTIVE) & 1)) * 2 + (RL(F_SIDE) & 1);
    const int iA = (((((RL(F_ITEM_EFFECT) & 15) * 3 + sclamp(RL(F_GENDER), 0, 2)) * 2 +
                      (RL(F_BCB) & 1)) * 2 + (RL(F_TRAPPED) & 1)) * 2 +
                    (RL(F_NEWSW) & 1)) * 2 + (RL(F_FAINTED) & 1);
    const int iSP = sclamp(RL(F_SPECIES), 0, 1025);
    const int iAB = sclamp(RL(F_ABILITY), 0, 299);
    const int iIT = sclamp(RL(F_ITEM), 0, 499);
    const float hp = (float)RL(F_HP);
    int mh = RL(F_MAXHP); if (mh < 1) mh = 1;
    const float ratio = fminf(fmaxf(hp / (float)mh, 0.f), 1.f);
    const int tok = __builtin_amdgcn_readfirstlane((int)floorf(1023.f * ratio));
    const int iLV = RL(F_LEVEL) & 127;
    const int b0 = RL(F_BOOST0 + 0), b1 = RL(F_BOOST0 + 1), b2 = RL(F_BOOST0 + 2),
              b3 = RL(F_BOOST0 + 3), b4 = RL(F_BOOST0 + 4), b5 = RL(F_BOOST0 + 5),
              b6 = RL(F_BOOST0 + 6);
    const int vp0 = ((RL(F_VOL0 + 0) & 15) << 4) | (RL(F_VOL0 + 1) & 15);
    const int vp1 = ((RL(F_VOL0 + 2) & 15) << 4) | (RL(F_VOL0 + 3) & 15);
    const int vp2 = ((RL(F_VOL0 + 4) & 15) << 4) | (RL(F_VOL0 + 5) & 15);
    const int v6  = RL(F_VOL0 + 6) & 15;
    const int m0 = sclamp(RL(F_MOVEID0 + 0), 0, 919), m1 = sclamp(RL(F_MOVEID0 + 1), 0, 919),
              m2 = sclamp(RL(F_MOVEID0 + 2), 0, 919), m3 = sclamp(RL(F_MOVEID0 + 3), 0, 919);
    const int p0 = RL(F_MOVEPP0 + 0) & 63, p1 = RL(F_MOVEPP0 + 1) & 63,
              p2 = RL(F_MOVEPP0 + 2) & 63, p3 = RL(F_MOVEPP0 + 3) & 63;
#undef RL

    // ---- 19 fp16 gathers, one independent batch ----
    const float4 xCB = ldh4(CB + iB * ES + d0);
    const float4 xCA = ldh4(CA + iA * ES + d0);
    const float4 xSP = ldh4(SP + iSP * ES + d0);
    const float4 xAB = ldh4(AB + iAB * ES + d0);
    const float4 xIT = ldh4(EI + iIT * ES + d0);
    const float4 xHP = ldh4(Hp + tok * ES + d0);
    const float4 xLV = ldh4(Lv + iLV * ES + d0);
    const float4 xV0 = ldh4(VP + (0 * 256 + vp0) * ES + d0);
    const float4 xV1 = ldh4(VP + (1 * 256 + vp1) * ES + d0);
    const float4 xV2 = ldh4(VP + (2 * 256 + vp2) * ES + d0);
    const float4 xV6 = ldh4(VP + (768 + v6) * ES + d0);
    const float4 xP0 = ldh4(Pp + p0 * ES + d0);
    const float4 xP1 = ldh4(Pp + p1 * ES + d0);
    const float4 xP2 = ldh4(Pp + p2 * ES + d0);
    const float4 xP3 = ldh4(Pp + p3 * ES + d0);
    const float4 xE0 = ldh4(EM + m0 * ES + d0);
    const float4 xE1 = ldh4(EM + m1 * ES + d0);
    const float4 xE2 = ldh4(EM + m2 * ES + d0);
    const float4 xE3 = ldh4(EM + m3 * ES + d0);

    // ---- tree combine ----
    float4 s0 = sum4(sum4(xCB, xCA), sum4(xSP, xAB));
    float4 s1 = sum4(sum4(xIT, xHP), sum4(xLV, xV6));
    float4 s2 = sum4(sum4(xV0, xV1), sum4(xV2, xP0));
    float4 s3 = sum4(sum4(xE0, xE1), sum4(xE2, xE3));
    float4 s4 = sum4(sum4(xP1, xP2), xP3);
    float4 acc = sum4(sum4(s0, s1), sum4(s2, s3));
    add4(acc, s4);

    // ---- LDS rows: ratio*OH0 + boosts ----
    fma4(acc, ratio, ld4(&lds[7 * ES + d0]));
    fma4(acc, 0.5f * (float)b0, ld4(&lds[0 * ES + d0]));
    fma4(acc, 0.5f * (float)b1, ld4(&lds[1 * ES + d0]));
    fma4(acc, 0.5f * (float)b2, ld4(&lds[2 * ES + d0]));
    fma4(acc, 0.5f * (float)b3, ld4(&lds[3 * ES + d0]));
    fma4(acc, 0.5f * (float)b4, ld4(&lds[4 * ES + d0]));
    fma4(acc, 0.5f * (float)b5, ld4(&lds[5 * ES + d0]));
    fma4(acc, 0.5f * (float)b6, ld4(&lds[6 * ES + d0]));

    st4_nt(out + went * ES + d0, acc);   // streaming store
}

// ---------------- host launch ----------------

extern "C" void kernel_launch(void* const* d_in, const int* in_sizes, int n_in,
                              void* d_out, int out_size, void* d_ws, size_t ws_size,
                              hipStream_t stream) {
    const int*   entities = (const int*)  d_in[0];
    const float* sp       = (const float*)d_in[1];
    const float* ab       = (const float*)d_in[2];
    const float* item_e   = (const float*)d_in[3];
    const float* moves_e  = (const float*)d_in[4];
    const float* hp_W     = (const float*)d_in[5];
    const float* hp_b     = (const float*)d_in[6];
    const float* level_W  = (const float*)d_in[7];
    const float* level_b  = (const float*)d_in[8];
    const float* active_W = (const float*)d_in[9];
    const float* active_b = (const float*)d_in[10];
    const float* onehot_W = (const float*)d_in[11];
    const float* onehot_b = (const float*)d_in[12];
    const float* boosts_W = (const float*)d_in[13];
    const float* boosts_b = (const float*)d_in[14];
    const float* vol_W    = (const float*)d_in[15];
    const float* vol_b    = (const float*)d_in[16];
    const float* item_W   = (const float*)d_in[17];
    const float* item_b   = (const float*)d_in[18];
    const float* side_W   = (const float*)d_in[19];
    const float* side_b   = (const float*)d_in[20];
    const float* moves_W  = (const float*)d_in[21];
    const float* moves_b  = (const float*)d_in[22];

    __half* wh  = (__half*)d_ws;
    float*  out = (float*)d_out;

    k_tables<<<TB_TOT, 256, 0, stream>>>(
        sp, ab, item_e, moves_e, hp_W, level_W, moves_W, vol_W,
        item_W, onehot_W, active_W, side_W,
        hp_b, level_b, active_b, onehot_b, boosts_b,
        vol_b, item_b, side_b, moves_b, wh);

    k_main<<<NENT / 4, 256, 0, stream>>>(entities, onehot_W, boosts_W, wh, out);
}

// Round 10
// 212.002 us; speedup vs baseline: 1.5992x; 1.0985x over previous
//
#include <hip/hip_runtime.h>
#include <hip/hip_fp16.h>

// ---------------- problem constants (match reference) ----------------
#define ES 256
#define NFEAT 42
#define NENT (8192 * 12)   // 98304 entities

// feature indices
#define F_SPECIES 0
#define F_ABILITY 1
#define F_ITEM 2
#define F_ITEM_EFFECT 3
#define F_GENDER 4
#define F_STATUS 5
#define F_BCB 6
#define F_TRAPPED 7
#define F_NEWSW 8
#define F_TOXIC 9
#define F_SLEEP 10
#define F_FAINTED 11
#define F_ACTIVE 12
#define F_SIDE 13
#define F_LEVEL 14
#define F_HP 15
#define F_MAXHP 16
#define F_BOOST0 17   // 7 boosts: 17..23
#define F_VOL0 24    // 9 vols: 24..32 (only first 7 matter after [:105] truncation)
#define F_MOVEID0 33  // 4 move ids
#define F_MOVEPP0 37  // 4 move pp

// ---------------- workspace layout (UNITS: halves) — all tables fp16 ----------------
#define OFF_HP     0                        // 1024 rows (10-bit hp-token)
#define OFF_LV     (OFF_HP + 1024*ES)       //  128 rows (7-bit level)
#define OFF_PP     (OFF_LV + 128*ES)        //   64 rows (6-bit movepp; row0 = 0)
#define OFF_VP     (OFF_PP + 64*ES)         //  784 rows (vol pairs t=0,1,2 + v6 single)
#define OFF_CA     (OFF_VP + 784*ES)        //  768 rows
#define OFF_CB     (OFF_CA + 768*ES)        // 1024 rows (+ all biases)
#define OFF_EI     (OFF_CB + 1024*ES)       //  500 rows (embed_item @ item_W[:256])
#define OFF_EM     (OFF_EI + 500*ES)        //  920 rows (embed_moves @ moves_W[:256])
#define OFF_SP     (OFF_EM + 920*ES)        // 1026 rows (fp16 copy of embed_species)
#define OFF_AB     (OFF_SP + 1026*ES)       //  300 rows (fp16 copy of embed_ability)
#define WS_HALVES  (OFF_AB + 300*ES)        // ~3.35 MB (fits per-XCD L2)

// ---------------- helpers ----------------
typedef float vf4 __attribute__((ext_vector_type(4)));

__device__ __forceinline__ float4 ld4(const float* p) {
    return *reinterpret_cast<const float4*>(p);
}
__device__ __forceinline__ void st4(float* p, const float4 v) {
    *reinterpret_cast<float4*>(p) = v;
}
__device__ __forceinline__ void st4_nt(float* p, const float4 v) {
    vf4 t = {v.x, v.y, v.z, v.w};
    __builtin_nontemporal_store(t, reinterpret_cast<vf4*>(p));
}
__device__ __forceinline__ void add4(float4& a, const float4 b) {
    a.x += b.x; a.y += b.y; a.z += b.z; a.w += b.w;
}
__device__ __forceinline__ float4 sum4(const float4 a, const float4 b) {
    return make_float4(a.x + b.x, a.y + b.y, a.z + b.z, a.w + b.w);
}
__device__ __forceinline__ void fma4(float4& a, float s, const float4 b) {
    a.x += s * b.x; a.y += s * b.y; a.z += s * b.z; a.w += s * b.w;
}
__device__ __forceinline__ int sclamp(int x, int lo, int hi) {
    return x < lo ? lo : (x > hi ? hi : x);
}
// store 4 floats as 4 halves (8B)
__device__ __forceinline__ void st4h(__half* p, const float4 v) {
    __half2 a = __floats2half2_rn(v.x, v.y);
    __half2 b = __floats2half2_rn(v.z, v.w);
    uint2 u;
    u.x = *reinterpret_cast<unsigned*>(&a);
    u.y = *reinterpret_cast<unsigned*>(&b);
    *reinterpret_cast<uint2*>(p) = u;
}

// ---------------- fused precompute kernel (4 rows/block, fp16 out) ----------------
#define TB_HP0 0        //  256 blocks
#define TB_LV0 256      //   32 blocks
#define TB_PP0 288      //   16 blocks
#define TB_VP0 304      //  196 blocks
#define TB_CA0 500      //  192 blocks
#define TB_CB0 692      //  256 blocks
#define TB_EI0 948      //  125 blocks
#define TB_EM0 1073     //  230 blocks
#define TB_SP0 1303     //  257 blocks (1026 rows, guarded)
#define TB_AB0 1560     //   75 blocks
#define TB_TOT 1635

__global__ __launch_bounds__(256) void k_tables(
    const float* __restrict__ sp_e, const float* __restrict__ ab_e,
    const float* __restrict__ item_e, const float* __restrict__ moves_e,
    const float* __restrict__ hp_W, const float* __restrict__ level_W,
    const float* __restrict__ moves_W, const float* __restrict__ vol_W,
    const float* __restrict__ item_W, const float* __restrict__ onehot_W,
    const float* __restrict__ active_W, const float* __restrict__ side_W,
    const float* __restrict__ hp_b, const float* __restrict__ level_b,
    const float* __restrict__ active_b, const float* __restrict__ onehot_b,
    const float* __restrict__ boosts_b, const float* __restrict__ vol_b,
    const float* __restrict__ item_b, const float* __restrict__ side_b,
    const float* __restrict__ moves_b,
    __half* __restrict__ wh) {
    __shared__ float4 se4[4][64];
    const int bid = blockIdx.x, tid = threadIdx.x;
    const int rl = tid >> 6, lane = tid & 63, d0 = lane * 4;
    float4 acc = make_float4(0.f, 0.f, 0.f, 0.f);

    if (bid < TB_LV0) {                       // ---- Hp
        int v = (bid - TB_HP0) * 4 + rl;
        for (int b = 0; b < 10; ++b)
            if ((v >> b) & 1) add4(acc, ld4(hp_W + b * ES + d0));
        st4h(wh + OFF_HP + v * ES + d0, acc);
    } else if (bid < TB_PP0) {                // ---- Lv
        int v = (bid - TB_LV0) * 4 + rl;
        for (int b = 0; b < 7; ++b)
            if ((v >> b) & 1) add4(acc, ld4(level_W + b * ES + d0));
        st4h(wh + OFF_LV + v * ES + d0, acc);
    } else if (bid < TB_VP0) {                // ---- Pp
        int v = (bid - TB_PP0) * 4 + rl;
        for (int b = 0; b < 6; ++b)
            if ((v >> b) & 1) add4(acc, ld4(moves_W + (256 + b) * ES + d0));
        st4h(wh + OFF_PP + v * ES + d0, acc);
    } else if (bid < TB_CA0) {                // ---- VP nibble pairs + v6 single
        int v = (bid - TB_VP0) * 4 + rl;
        if (v < 768) {
            int t = v >> 8, pair = v & 255, a = pair >> 4, b = pair & 15;
            for (int j = 0; j < 16; ++j) {
                if (a & j) add4(acc, ld4(vol_W + (32 * t + j) * ES + d0));
                if (b & j) add4(acc, ld4(vol_W + (32 * t + 16 + j) * ES + d0));
            }
        } else {
            int a = v - 768;
            for (int j = 0; j < 9; ++j)       // rows 96..104 (< 105 truncation)
                if (a & j) add4(acc, ld4(vol_W + (96 + j) * ES + d0));
        }
        st4h(wh + OFF_VP + v * ES + d0, acc);
    } else if (bid < TB_CB0) {                // ---- combA
        int idx = (bid - TB_CA0) * 4 + rl;
        int fa = idx & 1, ns = (idx >> 1) & 1, tr = (idx >> 2) & 1, bcb = (idx >> 3) & 1;
        int rest = idx >> 4, g = rest % 3, e = rest / 3;
        acc = sum4(sum4(ld4(item_W + (256 + e) * ES + d0), ld4(onehot_W + (1 + g) * ES + d0)),
                   sum4(ld4(onehot_W + (12 + bcb) * ES + d0), ld4(onehot_W + (14 + tr) * ES + d0)));
        add4(acc, sum4(ld4(onehot_W + (16 + ns) * ES + d0), ld4(onehot_W + (30 + fa) * ES + d0)));
        st4h(wh + OFF_CA + idx * ES + d0, acc);
    } else if (bid < TB_EI0) {                // ---- combB (+ all biases)
        int idx = (bid - TB_CB0) * 4 + rl;
        int sd = idx & 1, act = (idx >> 1) & 1, sl = (idx >> 2) & 3,
            tox = (idx >> 4) & 7, st = idx >> 7;
        acc = sum4(sum4(ld4(hp_b + d0), ld4(level_b + d0)),
                   sum4(ld4(active_b + d0), ld4(onehot_b + d0)));
        add4(acc, sum4(ld4(boosts_b + d0), ld4(vol_b + d0)));
        add4(acc, sum4(ld4(item_b + d0), ld4(side_b + d0)));
        fma4(acc, 4.0f, ld4(moves_b + d0));
        add4(acc, sum4(ld4(onehot_W + (4 + st) * ES + d0), ld4(onehot_W + (18 + tox) * ES + d0)));
        add4(acc, sum4(ld4(onehot_W + (26 + sl) * ES + d0),
                       sum4(ld4(active_W + act * ES + d0), ld4(side_W + sd * ES + d0))));
        st4h(wh + OFF_CB + idx * ES + d0, acc);
    } else if (bid < TB_SP0) {                // ---- embmm: Eitem / Emoves
        const float* E; const float* W; __half* o; int r0;
        if (bid < TB_EM0) { E = item_e;  W = item_W;  o = wh + OFF_EI; r0 = (bid - TB_EI0) * 4; }
        else              { E = moves_e; W = moves_W; o = wh + OFF_EM; r0 = (bid - TB_EM0) * 4; }
        se4[tid >> 6][tid & 63] = ld4(E + r0 * ES + tid * 4);   // 4 rows staged
        __syncthreads();
#pragma unroll 4
        for (int k0 = 0; k0 < 64; ++k0) {
            float4 e4 = se4[rl][k0];
            fma4(acc, e4.x, ld4(W + (4 * k0 + 0) * ES + d0));
            fma4(acc, e4.y, ld4(W + (4 * k0 + 1) * ES + d0));
            fma4(acc, e4.z, ld4(W + (4 * k0 + 2) * ES + d0));
            fma4(acc, e4.w, ld4(W + (4 * k0 + 3) * ES + d0));
        }
        st4h(o + (r0 + rl) * ES + d0, acc);
    } else if (bid < TB_AB0) {                // ---- fp16 copy of embed_species
        int r = (bid - TB_SP0) * 4 + rl;
        if (r < 1026) st4h(wh + OFF_SP + r * ES + d0, ld4(sp_e + r * ES + d0));
    } else {                                  // ---- fp16 copy of embed_ability
        int r = (bid - TB_AB0) * 4 + rl;
        st4h(wh + OFF_AB + r * ES + d0, ld4(ab_e + r * ES + d0));
    }
}

// ---------------- main gather kernel: TWO entities per wave ----------------
// Lanes 0-31 = entity A, lanes 32-63 = entity B; each lane owns 8 dims (16B fp16).
// Per-wave VMEM: 2 feature loads + 19 gathers + 4 stores = 25 for 2 entities.

__global__ __launch_bounds__(256) void k_main(
    const int* __restrict__ ent,
    const float* __restrict__ onehotW, const float* __restrict__ boostsW,
    const __half* __restrict__ wh,
    float* __restrict__ out) {
    __shared__ float lds[8 * ES];
    {   // stage 8 fixed f32 rows: 7 boostsW + onehot_W row0
        int t = threadIdx.x;
        int row = t >> 5, col = (t & 31) * 8;
        const float* src = (row < 7) ? (boostsW + row * ES + col) : (onehotW + col);
        st4(&lds[row * ES + col], ld4(src));
        st4(&lds[row * ES + col + 4], ld4(src + 4));
    }
    __syncthreads();

    const int lane  = threadIdx.x & 63;
    const int wpair = __builtin_amdgcn_readfirstlane((blockIdx.x * 256 + threadIdx.x) >> 6);
    const int entA  = wpair * 2;            // this wave: entities entA, entA+1
    const int e     = lane >> 5;            // 0 = entity A half, 1 = entity B half
    const int sub   = lane & 31;
    const int sub8  = sub * 8;              // dim offset (in halves / floats)
    const int base  = entA * NFEAT;

    // feature vectors: flat ints [0..83] over the two entities
    const int fv  = __builtin_nontemporal_load(ent + base + lane);        // flats 0..63
    const int fv2 = __builtin_nontemporal_load(ent + base + 52 + sub);    // flats 52..83

    // RLA(i): entity A feature i (flat i < 42, from fv).
    // RLB(i): entity B feature i (flat 42+i): fv if 42+i<64, else fv2 lane (i-10).
#define RLA(i) __builtin_amdgcn_readlane(fv, (i))
#define RLB(i) ((i) < 22 ? __builtin_amdgcn_readlane(fv, 42 + (i)) \
                         : __builtin_amdgcn_readlane(fv2, (i) - 10))

    const __half* Hp = wh + OFF_HP;
    const __half* Lv = wh + OFF_LV;
    const __half* Pp = wh + OFF_PP;
    const __half* VP = wh + OFF_VP;
    const __half* CA = wh + OFF_CA;
    const __half* CB = wh + OFF_CB;
    const __half* EI = wh + OFF_EI;
    const __half* EM = wh + OFF_EM;
    const __half* SP = wh + OFF_SP;
    const __half* AB = wh + OFF_AB;

    // ---- per-entity scalar indices (computed twice, SALU) ----
#define IDX_BLOCK(RL, S) \
    const int iCB##S = ((((RL(F_STATUS) & 7) * 8 + (RL(F_TOXIC) & 7)) * 4 + (RL(F_SLEEP) & 3)) * 2 + \
                        (RL(F_ACTIVE) & 1)) * 2 + (RL(F_SIDE) & 1); \
    const int iCA##S = (((((RL(F_ITEM_EFFECT) & 15) * 3 + sclamp(RL(F_GENDER), 0, 2)) * 2 + \
                          (RL(F_BCB) & 1)) * 2 + (RL(F_TRAPPED) & 1)) * 2 + \
                        (RL(F_NEWSW) & 1)) * 2 + (RL(F_FAINTED) & 1); \
    const int iSP##S = sclamp(RL(F_SPECIES), 0, 1025); \
    const int iAB##S = sclamp(RL(F_ABILITY), 0, 299); \
    const int iIT##S = sclamp(RL(F_ITEM), 0, 499); \
    float hpv##S = (float)RL(F_HP); \
    int mh##S = RL(F_MAXHP); if (mh##S < 1) mh##S = 1; \
    const float ratio##S = fminf(fmaxf(hpv##S / (float)mh##S, 0.f), 1.f); \
    const int tok##S = (int)floorf(1023.f * ratio##S); \
    const int iLV##S = RL(F_LEVEL) & 127; \
    const int vp0##S = ((RL(F_VOL0 + 0) & 15) << 4) | (RL(F_VOL0 + 1) & 15); \
    const int vp1##S = ((RL(F_VOL0 + 2) & 15) << 4) | (RL(F_VOL0 + 3) & 15); \
    const int vp2##S = ((RL(F_VOL0 + 4) & 15) << 4) | (RL(F_VOL0 + 5) & 15); \
    const int v6##S  = RL(F_VOL0 + 6) & 15; \
    const int m0##S = sclamp(RL(F_MOVEID0 + 0), 0, 919), m1##S = sclamp(RL(F_MOVEID0 + 1), 0, 919), \
              m2##S = sclamp(RL(F_MOVEID0 + 2), 0, 919), m3##S = sclamp(RL(F_MOVEID0 + 3), 0, 919); \
    const int p0##S = RL(F_MOVEPP0 + 0) & 63, p1##S = RL(F_MOVEPP0 + 1) & 63, \
              p2##S = RL(F_MOVEPP0 + 2) & 63, p3##S = RL(F_MOVEPP0 + 3) & 63; \
    const float b0##S = (float)RL(F_BOOST0 + 0), b1##S = (float)RL(F_BOOST0 + 1), \
                b2##S = (float)RL(F_BOOST0 + 2), b3##S = (float)RL(F_BOOST0 + 3), \
                b4##S = (float)RL(F_BOOST0 + 4), b5##S = (float)RL(F_BOOST0 + 5), \
                b6##S = (float)RL(F_BOOST0 + 6);

    IDX_BLOCK(RLA, A)
    IDX_BLOCK(RLB, B)
#undef RLA
#undef RLB
#undef IDX_BLOCK

    // ---- per-lane entity select (one cndmask each) ----
#define SEL(x) (e ? x##B : x##A)
    const int jCB = SEL(iCB), jCA = SEL(iCA), jSP = SEL(iSP), jAB = SEL(iAB), jIT = SEL(iIT);
    const int jHP = SEL(tok), jLV = SEL(iLV);
    const int jV0 = SEL(vp0), jV1 = SEL(vp1), jV2 = SEL(vp2), jV6 = SEL(v6);
    const int jP0 = SEL(p0), jP1 = SEL(p1), jP2 = SEL(p2), jP3 = SEL(p3);
    const int jM0 = SEL(m0), jM1 = SEL(m1), jM2 = SEL(m2), jM3 = SEL(m3);
    const float ratio = SEL(ratio);
    const float s0v = 0.5f * SEL(b0), s1v = 0.5f * SEL(b1), s2v = 0.5f * SEL(b2),
                s3v = 0.5f * SEL(b3), s4v = 0.5f * SEL(b4), s5v = 0.5f * SEL(b5),
                s6v = 0.5f * SEL(b6);
#undef SEL

    // ---- 19 gathers (dwordx4 = 8 halves/lane; half-wave per entity) ----
#define LD8(n, tab, idx) const uint4 n = *reinterpret_cast<const uint4*>((tab) + (idx) * ES + sub8)
    LD8(uCB, CB, jCB);
    LD8(uCA, CA, jCA);
    LD8(uSP, SP, jSP);
    LD8(uAB, AB, jAB);
    LD8(uIT, EI, jIT);
    LD8(uHP, Hp, jHP);
    LD8(uLV, Lv, jLV);
    LD8(uV0, VP, 0 * 256 + jV0);
    LD8(uV1, VP, 1 * 256 + jV1);
    LD8(uV2, VP, 2 * 256 + jV2);
    LD8(uV6, VP, 768 + jV6);
    LD8(uP0, Pp, jP0);
    LD8(uP1, Pp, jP1);
    LD8(uP2, Pp, jP2);
    LD8(uP3, Pp, jP3);
    LD8(uE0, EM, jM0);
    LD8(uE1, EM, jM1);
    LD8(uE2, EM, jM2);
    LD8(uE3, EM, jM3);
#undef LD8

    float4 a0 = make_float4(0.f, 0.f, 0.f, 0.f);
    float4 a1 = make_float4(0.f, 0.f, 0.f, 0.f);
#define ACC(u) { \
    __half2 h; float2 f; \
    h = *reinterpret_cast<const __half2*>(&u.x); f = __half22float2(h); a0.x += f.x; a0.y += f.y; \
    h = *reinterpret_cast<const __half2*>(&u.y); f = __half22float2(h); a0.z += f.x; a0.w += f.y; \
    h = *reinterpret_cast<const __half2*>(&u.z); f = __half22float2(h); a1.x += f.x; a1.y += f.y; \
    h = *reinterpret_cast<const __half2*>(&u.w); f = __half22float2(h); a1.z += f.x; a1.w += f.y; }
    ACC(uCB) ACC(uCA) ACC(uSP) ACC(uAB) ACC(uIT) ACC(uHP) ACC(uLV)
    ACC(uV0) ACC(uV1) ACC(uV2) ACC(uV6)
    ACC(uP0) ACC(uP1) ACC(uP2) ACC(uP3)
    ACC(uE0) ACC(uE1) ACC(uE2) ACC(uE3)
#undef ACC

    // ---- LDS fixed rows (f32): ratio * onehot_row0 + 7 scaled boosts ----
    fma4(a0, ratio, ld4(&lds[7 * ES + sub8]));     fma4(a1, ratio, ld4(&lds[7 * ES + sub8 + 4]));
    fma4(a0, s0v, ld4(&lds[0 * ES + sub8]));       fma4(a1, s0v, ld4(&lds[0 * ES + sub8 + 4]));
    fma4(a0, s1v, ld4(&lds[1 * ES + sub8]));       fma4(a1, s1v, ld4(&lds[1 * ES + sub8 + 4]));
    fma4(a0, s2v, ld4(&lds[2 * ES + sub8]));       fma4(a1, s2v, ld4(&lds[2 * ES + sub8 + 4]));
    fma4(a0, s3v, ld4(&lds[3 * ES + sub8]));       fma4(a1, s3v, ld4(&lds[3 * ES + sub8 + 4]));
    fma4(a0, s4v, ld4(&lds[4 * ES + sub8]));       fma4(a1, s4v, ld4(&lds[4 * ES + sub8 + 4]));
    fma4(a0, s5v, ld4(&lds[5 * ES + sub8]));       fma4(a1, s5v, ld4(&lds[5 * ES + sub8 + 4]));
    fma4(a0, s6v, ld4(&lds[6 * ES + sub8]));       fma4(a1, s6v, ld4(&lds[6 * ES + sub8 + 4]));

    // ---- store: each half-wave writes its entity's contiguous 1 KB ----
    float* op = out + (entA + e) * ES + sub8;
    st4_nt(op, a0);
    st4_nt(op + 4, a1);
}

// ---------------- host launch ----------------

extern "C" void kernel_launch(void* const* d_in, const int* in_sizes, int n_in,
                              void* d_out, int out_size, void* d_ws, size_t ws_size,
                              hipStream_t stream) {
    const int*   entities = (const int*)  d_in[0];
    const float* sp       = (const float*)d_in[1];
    const float* ab       = (const float*)d_in[2];
    const float* item_e   = (const float*)d_in[3];
    const float* moves_e  = (const float*)d_in[4];
    const float* hp_W     = (const float*)d_in[5];
    const float* hp_b     = (const float*)d_in[6];
    const float* level_W  = (const float*)d_in[7];
    const float* level_b  = (const float*)d_in[8];
    const float* active_W = (const float*)d_in[9];
    const float* active_b = (const float*)d_in[10];
    const float* onehot_W = (const float*)d_in[11];
    const float* onehot_b = (const float*)d_in[12];
    const float* boosts_W = (const float*)d_in[13];
    const float* boosts_b = (const float*)d_in[14];
    const float* vol_W    = (const float*)d_in[15];
    const float* vol_b    = (const float*)d_in[16];
    const float* item_W   = (const float*)d_in[17];
    const float* item_b   = (const float*)d_in[18];
    const float* side_W   = (const float*)d_in[19];
    const float* side_b   = (const float*)d_in[20];
    const float* moves_W  = (const float*)d_in[21];
    const float* moves_b  = (const float*)d_in[22];

    __half* wh  = (__half*)d_ws;
    float*  out = (float*)d_out;

    k_tables<<<TB_TOT, 256, 0, stream>>>(
        sp, ab, item_e, moves_e, hp_W, level_W, moves_W, vol_W,
        item_W, onehot_W, active_W, side_W,
        hp_b, level_b, active_b, onehot_b, boosts_b,
        vol_b, item_b, side_b, moves_b, wh);

    // 2 entities per wave, 4 waves per block -> 8 entities/block
    k_main<<<NENT / 8, 256, 0, stream>>>(entities, onehot_W, boosts_W, wh, out);
}